// Round 6
// baseline (7087.903 us; speedup 1.0000x reference)
//
#include <hip/hip_runtime.h>
#include <hip/hip_bf16.h>
#include <math.h>

typedef __hip_bfloat16 bf16;
#define T 1024

static __device__ __forceinline__ float b2f(bf16 x){ return __bfloat162float(x); }
static __device__ __forceinline__ bf16  f2b(float x){ return __float2bfloat16(x); }
static __device__ __forceinline__ float sig_(float x){ return 1.f/(1.f+__expf(-x)); }
static __device__ __forceinline__ float silu_(float x){ return x*sig_(x); }
static __device__ __forceinline__ float wsum(float v){
    #pragma unroll
    for (int m = 32; m >= 1; m >>= 1) v += __shfl_xor(v, m);
    return v;
}

// ---- kA: x3[b,t,o] = bng[o] * dot(x[b,t,:], sqw[o,:]) / sqrt(1+eps) + bnb[o]
__global__ __launch_bounds__(256) void kA(const float* __restrict__ x, const float* __restrict__ sqw,
                                          const float* __restrict__ bng, const float* __restrict__ bnb,
                                          float* __restrict__ x3) {
    int gid = blockIdx.x * 256 + threadIdx.x;   // 131072 = 4*1024*32
    int o = gid & 31, bt = gid >> 5;
    const float* xr = x + (size_t)bt * 64;
    const float* wr = sqw + (size_t)o * 64;
    float acc = 0.f;
    for (int i = 0; i < 64; ++i) acc += xr[i] * wr[i];
    x3[(size_t)bt * 32 + o] = bng[o] * acc * 0.9999950000374997f + bnb[o];
}

// ---- kB: xp3[t<T-1] = x3[t]*(w0-1) + x3[t+1]*w1 + x3[t+2]*w2 (x3[T]:=0); xp3[T-1] = x3[T-1]
__global__ __launch_bounds__(256) void kB(const float* __restrict__ x3, const float* __restrict__ dww,
                                          float* __restrict__ xp3) {
    int gid = blockIdx.x * 256 + threadIdx.x;   // 131072
    int o = gid & 31, bt = gid >> 5, t = bt & 1023;
    float v;
    if (t == 1023) {
        v = x3[(size_t)bt * 32 + o];
    } else {
        float x0 = x3[(size_t)bt * 32 + o];
        float x1 = x3[(size_t)(bt + 1) * 32 + o];
        float x2 = (t + 2 <= 1023) ? x3[(size_t)(bt + 2) * 32 + o] : 0.f;
        v = x0 * (dww[o * 3 + 0] - 1.f) + x1 * dww[o * 3 + 1] + x2 * dww[o * 3 + 2];
    }
    xp3[(size_t)bt * 32 + o] = v;
}

// ---- kC: xin[b,t,c] = x[b,t,c]*sigmoid(sum_o exw[c,o]*xp3[b,t,o]) + pos[t,c]
__global__ __launch_bounds__(256) void kC(const float* __restrict__ xp3, const float* __restrict__ exw,
                                          const float* __restrict__ x, const float* __restrict__ pos,
                                          float* __restrict__ xin) {
    int gid = blockIdx.x * 256 + threadIdx.x;   // 262144
    int c = gid & 63, bt = gid >> 6, t = bt & 1023;
    float g = 0.f;
    for (int o = 0; o < 32; ++o) g += exw[c * 32 + o] * xp3[(size_t)bt * 32 + o];
    xin[(size_t)bt * 64 + c] = x[(size_t)bt * 64 + c] * sig_(g) + pos[(size_t)t * 64 + c];
}

// ---- kD: q/k (dilated-causal conv, taps tt+2s-8, w[s=0] oldest), v/l pointwise; silu;
//          store scrambled: n=8b+(tt>>7), p=((tt&127)<<3)|h, c=o>>3 with o=c*8+h
__global__ __launch_bounds__(256) void kD(const float* __restrict__ xin,
        const float* __restrict__ wq, const float* __restrict__ bq,
        const float* __restrict__ wk, const float* __restrict__ bk,
        const float* __restrict__ wv, const float* __restrict__ wl,
        bf16* __restrict__ qq, bf16* __restrict__ kk, bf16* __restrict__ vv, bf16* __restrict__ ll) {
    int gid = blockIdx.x * 256 + threadIdx.x;   // 2097152 = 4*1024*512
    int o = gid & 511;
    int tt = (gid >> 9) & 1023;
    int b = gid >> 19;
    const float* xb = xin + (size_t)b * T * 64;
    float aq = bq[o], ak = bk[o];
    const float* wqr = wq + (size_t)o * 320;
    const float* wkr = wk + (size_t)o * 320;
    for (int i = 0; i < 64; ++i) {
        for (int s = 0; s < 5; ++s) {
            int ts = tt + 2 * s - 8;
            if (ts >= 0) {
                float xv = xb[(size_t)ts * 64 + i];
                aq += xv * wqr[i * 5 + s];
                ak += xv * wkr[i * 5 + s];
            }
        }
    }
    float av = 0.f, al = 0.f;
    const float* xr = xb + (size_t)tt * 64;
    const float* wvr = wv + (size_t)o * 64;
    const float* wlr = wl + (size_t)o * 64;
    for (int i = 0; i < 64; ++i) { av += xr[i] * wvr[i]; al += xr[i] * wlr[i]; }
    int c = o >> 3, h = o & 7;
    int n = (b << 3) + (tt >> 7);
    int p = ((tt & 127) << 3) | h;
    size_t idx = ((size_t)n * T + p) * 64 + c;
    const float isg = 0.35355339059327373f;     // 1/64^0.25
    qq[idx] = f2b(silu_(aq) * isg);
    kk[idx] = f2b(silu_(ak) * isg);
    vv[idx] = f2b(silu_(av));
    ll[idx] = f2b(silu_(al));
}

// ---- kE: local windowed causal softmax attention over pseudo rows (window 5)
__global__ __launch_bounds__(256) void kE(const bf16* __restrict__ ll, bf16* __restrict__ ol) {
    int gid = blockIdx.x * 256 + threadIdx.x;   // 32768
    int p = gid & 1023, n = gid >> 10;
    const bf16* base = ll + (size_t)n * T * 64;
    float s[6], mx = -1e30f;
    for (int u = 0; u < 6; ++u) {
        int j = p - 5 + u;
        if (j < 0) { s[u] = -1e30f; continue; }
        float d = 0.f;
        for (int c2 = 0; c2 < 64; ++c2) d += b2f(base[(size_t)j * 64 + c2]) * b2f(base[(size_t)p * 64 + c2]);
        s[u] = d * 0.125f;
        mx = fmaxf(mx, s[u]);
    }
    float P[6], Z = 0.f;
    for (int u = 0; u < 6; ++u) { P[u] = (s[u] <= -1e29f) ? 0.f : __expf(s[u] - mx); Z += P[u]; }
    float iZ = 1.f / Z;
    for (int c2 = 0; c2 < 64; ++c2) {
        float a = 0.f;
        for (int u = 0; u < 6; ++u) {
            int j = p - 5 + u;
            if (j >= 0) a += P[u] * b2f(base[(size_t)j * 64 + c2]);
        }
        ol[((size_t)n * T + p) * 64 + c2] = f2b(a * iZ);
    }
}

// ---- kF: global causal softmax attention, one wave per (n, p); lane = channel
__global__ __launch_bounds__(256) void kF(const bf16* __restrict__ qq, const bf16* __restrict__ kk,
                                          const bf16* __restrict__ vv, bf16* __restrict__ og) {
    int wid = (blockIdx.x << 2) | (threadIdx.x >> 6);   // 32768 waves
    int lane = threadIdx.x & 63;
    int p = wid & 1023, n = wid >> 10;
    float qv = b2f(qq[((size_t)n * T + p) * 64 + lane]);
    const bf16* kb = kk + (size_t)n * T * 64;
    const bf16* vb = vv + (size_t)n * T * 64;
    float m = -1e30f, Z = 0.f, acc = 0.f;
    for (int j = 0; j <= p; ++j) {
        float s = wsum(qv * b2f(kb[(size_t)j * 64 + lane]));
        float mn = fmaxf(m, s);
        float wo = __expf(m - mn), wn = __expf(s - mn);
        Z = Z * wo + wn;
        acc = acc * wo + wn * b2f(vb[(size_t)j * 64 + lane]);
        m = mn;
    }
    og[((size_t)n * T + p) * 64 + lane] = f2b(acc / Z);
}

// ---- kG: gate/concat + uni matmul + silu + residual + LN1 + FF + LN2 (fp32 output)
__global__ __launch_bounds__(256) void kG(const bf16* __restrict__ og, const bf16* __restrict__ ol,
        const float* __restrict__ uniw, const float* __restrict__ unib, const float* __restrict__ xin,
        const float* __restrict__ ln1g, const float* __restrict__ ln1b,
        const float* __restrict__ ffw1, const float* __restrict__ ffb1,
        const float* __restrict__ ffw2, const float* __restrict__ ffb2,
        const float* __restrict__ ln2g, const float* __restrict__ ln2b,
        float* __restrict__ out) {
    __shared__ float su[1024], sr[256], sy[64], sh[256];
    int b = blockIdx.x >> 10, p = blockIdx.x & 1023;
    int tid = threadIdx.x;
    for (int m = 0; m < 4; ++m) {
        int d = tid + (m << 8);
        int hh = d >> 6, cc = d & 63;
        size_t idx = ((size_t)((b << 3) + (hh & 7)) * T + p) * 64 + cc;
        float gv = b2f(og[idx]);
        float sg = sig_(gv);
        su[d] = (hh < 8) ? (1.f - sg) * b2f(ol[idx]) : sg * gv;
    }
    __syncthreads();
    int c = tid & 63, q = tid >> 6;
    float part = 0.f;
    for (int dd = 0; dd < 256; ++dd) {
        int d = (q << 8) + dd;
        part += su[d] * uniw[(size_t)d * 64 + c];
    }
    sr[tid] = part;
    __syncthreads();
    float y = 0.f;
    if (tid < 64) {
        float tot = sr[c] + sr[64 + c] + sr[128 + c] + sr[192 + c] + unib[c];
        float a = silu_(tot);
        float yv = a + xin[((size_t)(b * T + p)) * 64 + c];
        float mu = wsum(yv) * 0.015625f;
        float dv = yv - mu;
        float var = wsum(dv * dv) * 0.015625f;
        y = dv * rsqrtf(var + 1e-5f) * ln1g[c] + ln1b[c];
        sy[c] = y;
    }
    __syncthreads();
    {
        float hv = ffb1[tid];
        for (int i = 0; i < 64; ++i) hv += sy[i] * ffw1[i * 256 + tid];
        sh[tid] = fmaxf(hv, 0.f);
    }
    __syncthreads();
    if (tid < 64) {
        float f = ffb2[c];
        for (int j = 0; j < 256; ++j) f += sh[j] * ffw2[j * 64 + c];
        float z = f + y;
        float mu = wsum(z) * 0.015625f;
        float dv = z - mu;
        float var = wsum(dv * dv) * 0.015625f;
        out[((size_t)(b * T + p)) * 64 + c] = dv * rsqrtf(var + 1e-5f) * ln2g[c] + ln2b[c];
    }
}

extern "C" void kernel_launch(void* const* d_in, const int* in_sizes, int n_in,
                              void* d_out, int out_size, void* d_ws, size_t ws_size,
                              hipStream_t stream) {
    (void)in_sizes; (void)n_in; (void)out_size; (void)ws_size;
    const float* x    = (const float*)d_in[0];
    const float* sqw  = (const float*)d_in[1];
    const float* bng  = (const float*)d_in[2];
    const float* bnb  = (const float*)d_in[3];
    const float* dww  = (const float*)d_in[4];
    const float* exw  = (const float*)d_in[5];
    const float* pos  = (const float*)d_in[6];
    const float* wq   = (const float*)d_in[7];
    const float* bq   = (const float*)d_in[8];
    const float* wk   = (const float*)d_in[9];
    const float* bk   = (const float*)d_in[10];
    const float* wv   = (const float*)d_in[11];
    const float* wl   = (const float*)d_in[12];
    const float* uniw = (const float*)d_in[13];
    const float* unib = (const float*)d_in[14];
    const float* ln1g = (const float*)d_in[15];
    const float* ln1b = (const float*)d_in[16];
    const float* ln2g = (const float*)d_in[17];
    const float* ln2b = (const float*)d_in[18];
    const float* ffw1 = (const float*)d_in[19];
    const float* ffb1 = (const float*)d_in[20];
    const float* ffw2 = (const float*)d_in[21];
    const float* ffb2 = (const float*)d_in[22];

    // ws layout — 26 MiB total, no aliasing.
    char* ws = (char*)d_ws;
    float* xin = (float*)(ws);                    // fp32 1.0 MiB
    float* x3  = (float*)(ws + 0x100000);         // fp32 0.5 MiB
    float* xp3 = (float*)(ws + 0x180000);         // fp32 0.5 MiB
    bf16*  qq  = (bf16*)(ws + 0x200000);          // 4 MiB
    bf16*  kk  = (bf16*)(ws + 0x600000);          // 4 MiB
    bf16*  vv  = (bf16*)(ws + 0xA00000);          // 4 MiB
    bf16*  ll  = (bf16*)(ws + 0xE00000);          // 4 MiB
    bf16*  ogb = (bf16*)(ws + 0x1200000);         // 4 MiB
    bf16*  olb = (bf16*)(ws + 0x1600000);         // 4 MiB (end 0x1A00000)

    kA<<<512, 256, 0, stream>>>(x, sqw, bng, bnb, x3);
    kB<<<512, 256, 0, stream>>>(x3, dww, xp3);
    kC<<<1024, 256, 0, stream>>>(xp3, exw, x, pos, xin);
    kD<<<8192, 256, 0, stream>>>(xin, wq, bq, wk, bk, wv, wl, qq, kk, vv, ll);
    kE<<<128, 256, 0, stream>>>(ll, olb);
    kF<<<8192, 256, 0, stream>>>(qq, kk, vv, ogb);
    kG<<<4096, 256, 0, stream>>>(ogb, olb, uniw, unib, xin,
                                 ln1g, ln1b, ffw1, ffb1, ffw2, ffb2, ln2g, ln2b,
                                 (float*)d_out);
}

// Round 7
// 608.919 us; speedup vs baseline: 11.6401x; 11.6401x over previous
//
#include <hip/hip_runtime.h>
#include <hip/hip_bf16.h>
#include <math.h>

#define B 4
#define T 1024
#define KDIM 64
#define R 32
#define NH 8
#define NEGBIG (-1e30f)

typedef __hip_bfloat16 bf16;

static __device__ __forceinline__ float b2f(bf16 x) { return __bfloat162float(x); }
static __device__ __forceinline__ bf16 f2b(float x) { return __float2bfloat16(x); }
static __device__ __forceinline__ float sigmoidf_(float x) { return 1.0f / (1.0f + __expf(-x)); }
static __device__ __forceinline__ float siluf_(float x) { return x * sigmoidf_(x); }

static __device__ __forceinline__ float waveSum64(float v) {
    #pragma unroll
    for (int m = 32; m >= 1; m >>= 1) v += __shfl_xor(v, m);
    return v;
}
static __device__ __forceinline__ float grp8Sum(float v) {
    v += __shfl_xor(v, 1); v += __shfl_xor(v, 2); v += __shfl_xor(v, 4);
    return v;
}
static __device__ __forceinline__ float grp8Max(float v) {
    v = fmaxf(v, __shfl_xor(v, 1)); v = fmaxf(v, __shfl_xor(v, 2)); v = fmaxf(v, __shfl_xor(v, 4));
    return v;
}

// ---------------- Kernel 1a: x3 = bn(squeeze conv) ----------------
__global__ __launch_bounds__(256) void k1a_x3(const float* __restrict__ x, const float* __restrict__ sqw,
                                              const float* __restrict__ bng, const float* __restrict__ bnb,
                                              float* __restrict__ x3) {
    int blk = blockIdx.x;               // 512 blocks
    int b = blk >> 7, t0 = (blk & 127) << 3;
    int row = threadIdx.x >> 5, o = threadIdx.x & 31;
    int tt = t0 + row;
    const float* xr = x + (size_t)(b * T + tt) * KDIM;
    const float* wr = sqw + o * KDIM;
    float acc = 0.f;
    #pragma unroll
    for (int i = 0; i < KDIM; ++i) acc += xr[i] * wr[i];
    const float inv = 0.9999950000374997f; // 1/sqrt(1+1e-5)
    x3[(size_t)(b * T + tt) * R + o] = bng[o] * acc * inv + bnb[o];
}

// ---------------- Kernel 1b: depthwise diff + excite conv + gate + pos ----------------
__global__ __launch_bounds__(256) void k1b_xin(const float* __restrict__ x3, const float* __restrict__ dww,
                                               const float* __restrict__ exw, const float* __restrict__ x,
                                               const float* __restrict__ pos, float* __restrict__ xin) {
    __shared__ float sx3[10 * R];
    __shared__ float sxp[8 * R];
    int blk = blockIdx.x;               // 512 blocks
    int b = blk >> 7, t0 = (blk & 127) << 3;
    int tid = threadIdx.x;
    for (int e = tid; e < 320; e += 256) {
        int rr = e >> 5, o = e & 31;
        int tt = t0 + rr;
        sx3[e] = (tt < T) ? x3[(size_t)(b * T + tt) * R + o] : 0.f;
    }
    __syncthreads();
    {
        int rr = tid >> 5, o = tid & 31;
        int tt = t0 + rr;
        float v;
        if (tt == T - 1) {
            v = sx3[rr * R + o];
        } else {
            float w0 = dww[o * 3 + 0], w1 = dww[o * 3 + 1], w2 = dww[o * 3 + 2];
            v = sx3[rr * R + o] * (w0 - 1.f) + sx3[(rr + 1) * R + o] * w1 + sx3[(rr + 2) * R + o] * w2;
        }
        sxp[rr * R + o] = v;
    }
    __syncthreads();
    int rr = tid >> 5, c0 = tid & 31;
    int tt = t0 + rr;
    #pragma unroll
    for (int u = 0; u < 2; ++u) {
        int c = c0 + u * 32;
        const float* ew = exw + c * R;
        float g = 0.f;
        #pragma unroll
        for (int o = 0; o < R; ++o) g += ew[o] * sxp[rr * R + o];
        float sg = sigmoidf_(g);
        size_t idx = (size_t)(b * T + tt) * KDIM + c;
        xin[idx] = x[idx] * sg + pos[tt * KDIM + c];
    }
}

// ---------------- Kernel 2: q/k/v/l convs + silu + head-scramble store ----------------
// pseudo layout: n = b*8 + (tt>>7), p = ((tt&127)<<3)|(o&7), c = o>>3
__global__ __launch_bounds__(256) void k2_qkvl(const float* __restrict__ xin,
        const float* __restrict__ wq, const float* __restrict__ bq,
        const float* __restrict__ wk, const float* __restrict__ bk,
        const float* __restrict__ wv, const float* __restrict__ wl,
        bf16* __restrict__ qo, bf16* __restrict__ ko, bf16* __restrict__ vo, bf16* __restrict__ lo) {
    __shared__ float sx[16 * KDIM];
    int blk = blockIdx.x;               // 512 blocks
    int b = blk >> 7, p0 = (blk & 127) << 3;
    int tid = threadIdx.x;
    #pragma unroll
    for (int m = 0; m < 4; ++m) {
        int e = tid + 256 * m;
        int rr = e >> 6, c = e & 63;
        int tt = p0 - 8 + rr;
        sx[e] = (tt >= 0) ? xin[(size_t)(b * T + tt) * KDIM + c] : 0.f;
    }
    __syncthreads();
    const float inv_sg = 0.35355339059327373f; // 1/64^0.25
    // ---- q and k: dilated causal conv, taps real times (p0+p) + 2s - 8 ----
    for (int which = 0; which < 2; ++which) {
        const float* W = which ? wk : wq;
        const float* Bv = which ? bk : bq;
        bf16* Out = which ? ko : qo;
        #pragma unroll
        for (int oo = 0; oo < 2; ++oo) {
            int o = tid + oo * 256;
            float bias = Bv[o];
            float acc[8];
            #pragma unroll
            for (int p = 0; p < 8; ++p) acc[p] = bias;
            const float* wrow = W + (size_t)o * KDIM * 5;
            for (int i = 0; i < KDIM; ++i) {
                #pragma unroll
                for (int s = 0; s < 5; ++s) {
                    float w = wrow[i * 5 + s];
                    const float* xr = &sx[(2 * s) * KDIM + i];
                    #pragma unroll
                    for (int p = 0; p < 8; ++p) acc[p] += xr[p * KDIM] * w;
                }
            }
            int c = o >> 3, h = o & 7;
            #pragma unroll
            for (int p = 0; p < 8; ++p) {
                int tt = p0 + p;
                int n = b * NH + (tt >> 7);
                int pp = ((tt & 127) << 3) | h;
                Out[(size_t)(n * T + pp) * KDIM + c] = f2b(siluf_(acc[p]) * inv_sg);
            }
        }
    }
    // ---- v and l: pointwise ----
    for (int which = 0; which < 2; ++which) {
        const float* W = which ? wl : wv;
        bf16* Out = which ? lo : vo;
        #pragma unroll
        for (int oo = 0; oo < 2; ++oo) {
            int o = tid + oo * 256;
            const float* wrow = W + (size_t)o * KDIM;
            float acc[8];
            #pragma unroll
            for (int p = 0; p < 8; ++p) acc[p] = 0.f;
            for (int i = 0; i < KDIM; ++i) {
                float w = wrow[i];
                const float* xr = &sx[8 * KDIM + i];
                #pragma unroll
                for (int p = 0; p < 8; ++p) acc[p] += xr[p * KDIM] * w;
            }
            int c = o >> 3, h = o & 7;
            #pragma unroll
            for (int p = 0; p < 8; ++p) {
                int tt = p0 + p;
                int n = b * NH + (tt >> 7);
                int pp = ((tt & 127) << 3) | h;
                Out[(size_t)(n * T + pp) * KDIM + c] = f2b(siluf_(acc[p]));
            }
        }
    }
}

// ---------------- Kernel 3: local windowed causal attention (window 5) ----------------
__global__ __launch_bounds__(256) void k3_local(const bf16* __restrict__ lws, bf16* __restrict__ ol) {
    int wave = threadIdx.x >> 6, lane = threadIdx.x & 63;
    int ridx = blockIdx.x * 4 + wave;   // 8192 blocks -> 32768 rows
    int n = ridx >> 10, p = ridx & 1023;
    const bf16* base = lws + (size_t)n * T * KDIM;
    float lp = b2f(base[(size_t)p * KDIM + lane]);
    float lj[6], s[6];
    #pragma unroll
    for (int u = 0; u < 6; ++u) {
        int j = p - 5 + u;
        bool valid = (j >= 0);
        lj[u] = valid ? b2f(base[(size_t)j * KDIM + lane]) : 0.f;
        float d = lp * lj[u];
        d = waveSum64(d);
        s[u] = valid ? d * 0.125f : NEGBIG;
    }
    float mx = s[5];
    #pragma unroll
    for (int u = 0; u < 5; ++u) mx = fmaxf(mx, s[u]);
    float Z = 0.f, acc = 0.f;
    #pragma unroll
    for (int u = 0; u < 6; ++u) {
        float e = (s[u] <= NEGBIG) ? 0.f : __expf(s[u] - mx);
        Z += e;
        acc += e * lj[u];
    }
    ol[(size_t)(n * T + p) * KDIM + lane] = f2b(acc / Z);
}

// ---------------- Kernel 4: global causal flash attention ----------------
// og aliases q (in-place). Safe: this block's 32 q-rows are fully staged in LDS
// before any og store; no other block reads these q rows.
__global__ __launch_bounds__(256) void k4_flash(const bf16* __restrict__ qws, const bf16* __restrict__ kws,
                                                const bf16* __restrict__ vws, bf16* __restrict__ og) {
    __shared__ float sQ[32 * 65];
    __shared__ float sK[64 * 65];
    __shared__ __align__(16) float sV[64 * 64];
    __shared__ float sP[32 * 65];
    int n = blockIdx.x >> 5, it = blockIdx.x & 31;   // 1024 blocks
    int p0 = it << 5;
    int tid = threadIdx.x;
    const bf16* qb = qws + (size_t)(n * T + p0) * KDIM;
    #pragma unroll
    for (int m = 0; m < 8; ++m) {
        int e = tid + 256 * m;          // 0..2047
        int rr = e >> 6, c = e & 63;
        sQ[rr * 65 + c] = b2f(qb[e]);
    }
    int rr = tid >> 3, q8 = tid & 7;
    int prow = p0 + rr;
    float m_i = NEGBIG, l_i = 0.f;
    float o[8];
    #pragma unroll
    for (int c = 0; c < 8; ++c) o[c] = 0.f;
    int jtmax = (p0 + 31) >> 6;
    for (int jt = 0; jt <= jtmax; ++jt) {
        int j0 = jt << 6;
        __syncthreads();   // protect sK/sV/sP against previous iteration's readers
        const bf16* kb = kws + (size_t)(n * T + j0) * KDIM;
        const bf16* vb = vws + (size_t)(n * T + j0) * KDIM;
        #pragma unroll
        for (int m = 0; m < 16; ++m) {
            int e = tid + 256 * m;      // 0..4095
            int r2 = e >> 6, c2 = e & 63;
            sK[r2 * 65 + c2] = b2f(kb[e]);
            sV[r2 * 64 + c2] = b2f(vb[e]);
        }
        __syncthreads();
        float s[8];
        #pragma unroll
        for (int c = 0; c < 8; ++c) s[c] = 0.f;
        for (int i = 0; i < KDIM; ++i) {
            float qv = sQ[rr * 65 + i];
            #pragma unroll
            for (int c = 0; c < 8; ++c) s[c] += qv * sK[(q8 * 8 + c) * 65 + i];
        }
        #pragma unroll
        for (int c = 0; c < 8; ++c) {
            int j = j0 + q8 * 8 + c;
            if (j > prow) s[c] = NEGBIG;
        }
        float mt = s[0];
        #pragma unroll
        for (int c = 1; c < 8; ++c) mt = fmaxf(mt, s[c]);
        mt = grp8Max(mt);
        float mnew = fmaxf(m_i, mt);
        float alpha = __expf(m_i - mnew);
        float psum = 0.f;
        #pragma unroll
        for (int c = 0; c < 8; ++c) {
            float e = (s[c] <= NEGBIG) ? 0.f : __expf(s[c] - mnew);
            sP[rr * 65 + q8 * 8 + c] = e;
            psum += e;
        }
        psum = grp8Sum(psum);
        l_i = l_i * alpha + psum;
        m_i = mnew;
        #pragma unroll
        for (int c = 0; c < 8; ++c) o[c] *= alpha;
        __syncthreads();
        for (int j = 0; j < 64; ++j) {
            float pv = sP[rr * 65 + j];
            const float4 va = *(const float4*)&sV[j * 64 + q8 * 8];
            const float4 vb4 = *(const float4*)&sV[j * 64 + q8 * 8 + 4];
            o[0] += pv * va.x;  o[1] += pv * va.y;  o[2] += pv * va.z;  o[3] += pv * va.w;
            o[4] += pv * vb4.x; o[5] += pv * vb4.y; o[6] += pv * vb4.z; o[7] += pv * vb4.w;
        }
    }
    float invl = 1.f / l_i;
    bf16* ob = og + (size_t)(n * T + prow) * KDIM + q8 * 8;
    #pragma unroll
    for (int c = 0; c < 8; ++c) ob[c] = f2b(o[c] * invl);
}

// ---------------- Kernel 5: gate/concat + uni matmul + silu + residual + LN1 + FF + LN2 ----------------
__global__ __launch_bounds__(256) void k5_out(const bf16* __restrict__ og, const bf16* __restrict__ olw,
        const float* __restrict__ uniw, const float* __restrict__ unib, const float* __restrict__ xin,
        const float* __restrict__ ln1g, const float* __restrict__ ln1b,
        const float* __restrict__ ffw1, const float* __restrict__ ffb1,
        const float* __restrict__ ffw2, const float* __restrict__ ffb2,
        const float* __restrict__ ln2g, const float* __restrict__ ln2b,
        float* __restrict__ out) {
    __shared__ float su[1024];
    __shared__ float sr[256];
    __shared__ float sy[64];
    __shared__ float sh[256];
    int blk = blockIdx.x;               // 4096 blocks
    int b = blk >> 10, p = blk & 1023;
    int tid = threadIdx.x;
    #pragma unroll
    for (int m = 0; m < 4; ++m) {
        int d = tid + 256 * m;
        int hh = d >> 6, c = d & 63, hi = hh & 7;
        size_t idx = (size_t)((b * NH + hi) * T + p) * KDIM + c;
        float gv = b2f(og[idx]);
        float sg = sigmoidf_(gv);
        su[d] = (hh < 8) ? (1.f - sg) * b2f(olw[idx]) : sg * gv;
    }
    __syncthreads();
    int c = tid & 63, quarter = tid >> 6;
    float part = 0.f;
    for (int dd = 0; dd < 256; ++dd) {
        int d = quarter * 256 + dd;
        part += su[d] * uniw[(size_t)d * KDIM + c];
    }
    sr[tid] = part;
    __syncthreads();
    float y = 0.f;
    if (tid < 64) {
        float tot = sr[c] + sr[64 + c] + sr[128 + c] + sr[192 + c] + unib[c];
        float a = siluf_(tot);
        float yv = a + xin[(size_t)(b * T + p) * KDIM + c];
        float mean = waveSum64(yv) * (1.f / 64.f);
        float dv = yv - mean;
        float var = waveSum64(dv * dv) * (1.f / 64.f);
        y = dv * rsqrtf(var + 1e-5f) * ln1g[c] + ln1b[c];
        sy[c] = y;
    }
    __syncthreads();
    {
        int j = tid;
        float hv = ffb1[j];
        for (int i = 0; i < 64; ++i) hv += sy[i] * ffw1[i * 256 + j];
        sh[j] = fmaxf(hv, 0.f);
    }
    __syncthreads();
    if (tid < 64) {
        float f = ffb2[c];
        for (int j = 0; j < 256; ++j) f += sh[j] * ffw2[j * KDIM + c];
        float z = f + y;
        float mean = waveSum64(z) * (1.f / 64.f);
        float dv = z - mean;
        float var = waveSum64(dv * dv) * (1.f / 64.f);
        out[(size_t)(b * T + p) * KDIM + c] = dv * rsqrtf(var + 1e-5f) * ln2g[c] + ln2b[c];
    }
}

extern "C" void kernel_launch(void* const* d_in, const int* in_sizes, int n_in,
                              void* d_out, int out_size, void* d_ws, size_t ws_size,
                              hipStream_t stream) {
    (void)in_sizes; (void)n_in; (void)out_size; (void)ws_size;
    const float* x    = (const float*)d_in[0];
    const float* sqw  = (const float*)d_in[1];
    const float* bng  = (const float*)d_in[2];
    const float* bnb  = (const float*)d_in[3];
    const float* dww  = (const float*)d_in[4];
    const float* exw  = (const float*)d_in[5];
    const float* pos  = (const float*)d_in[6];
    const float* wq   = (const float*)d_in[7];
    const float* bq   = (const float*)d_in[8];
    const float* wk   = (const float*)d_in[9];
    const float* bk   = (const float*)d_in[10];
    const float* wv   = (const float*)d_in[11];
    const float* wl   = (const float*)d_in[12];
    const float* uniw = (const float*)d_in[13];
    const float* unib = (const float*)d_in[14];
    const float* ln1g = (const float*)d_in[15];
    const float* ln1b = (const float*)d_in[16];
    const float* ln2g = (const float*)d_in[17];
    const float* ln2b = (const float*)d_in[18];
    const float* ffw1 = (const float*)d_in[19];
    const float* ffb1 = (const float*)d_in[20];
    const float* ffw2 = (const float*)d_in[21];
    const float* ffb2 = (const float*)d_in[22];

    // ws layout — 21.5 MiB.
    char* ws = (char*)d_ws;
    float* xin = (float*)(ws);                    // fp32 1.0 MiB
    bf16*  qog = (bf16*)(ws + 0x100000);          // 4 MiB  q, then og in-place
    bf16*  kw_ = (bf16*)(ws + 0x500000);          // 4 MiB
    bf16*  vw_ = (bf16*)(ws + 0x900000);          // 4 MiB
    bf16*  lw_ = (bf16*)(ws + 0xD00000);          // 4 MiB
    bf16*  olw = (bf16*)(ws + 0x1100000);         // 4 MiB
    float* x3  = (float*)(ws + 0x1500000);        // fp32 0.5 MiB (end 0x1580000)

    k1a_x3 <<<512, 256, 0, stream>>>(x, sqw, bng, bnb, x3);
    k1b_xin<<<512, 256, 0, stream>>>(x3, dww, exw, x, pos, xin);
    k2_qkvl<<<512, 256, 0, stream>>>(xin, wq, bq, wk, bk, wv, wl, qog, kw_, vw_, lw_);
    k3_local<<<8192, 256, 0, stream>>>(lw_, olw);
    k4_flash<<<1024, 256, 0, stream>>>(qog, kw_, vw_, qog);   // og overwrites q in-place
    k5_out <<<4096, 256, 0, stream>>>(qog, olw, uniw, unib, xin,
                                      ln1g, ln1b, ffw1, ffb1, ffw2, ffb2, ln2g, ln2b,
                                      (float*)d_out);
}

// Round 8
// 340.176 us; speedup vs baseline: 20.8360x; 1.7900x over previous
//
#include <hip/hip_runtime.h>
#include <hip/hip_bf16.h>
#include <math.h>

#define B 4
#define T 1024
#define KDIM 64
#define R 32
#define NH 8
#define NEGBIG (-1e30f)

typedef __hip_bfloat16 bf16;

static __device__ __forceinline__ float b2f(bf16 x) { return __bfloat162float(x); }
static __device__ __forceinline__ bf16 f2b(float x) { return __float2bfloat16(x); }
static __device__ __forceinline__ float sigmoidf_(float x) { return 1.0f / (1.0f + __expf(-x)); }
static __device__ __forceinline__ float siluf_(float x) { return x * sigmoidf_(x); }

static __device__ __forceinline__ float waveSum64(float v) {
    #pragma unroll
    for (int m = 32; m >= 1; m >>= 1) v += __shfl_xor(v, m);
    return v;
}

// ---------------- Kernel 1a: x3 = bn(squeeze conv) ----------------
__global__ __launch_bounds__(256) void k1a_x3(const float* __restrict__ x, const float* __restrict__ sqw,
                                              const float* __restrict__ bng, const float* __restrict__ bnb,
                                              float* __restrict__ x3) {
    int blk = blockIdx.x;               // 512 blocks
    int b = blk >> 7, t0 = (blk & 127) << 3;
    int row = threadIdx.x >> 5, o = threadIdx.x & 31;
    int tt = t0 + row;
    const float* xr = x + (size_t)(b * T + tt) * KDIM;
    const float* wr = sqw + o * KDIM;
    float acc = 0.f;
    #pragma unroll
    for (int i = 0; i < KDIM; ++i) acc += xr[i] * wr[i];
    const float inv = 0.9999950000374997f; // 1/sqrt(1+1e-5)
    x3[(size_t)(b * T + tt) * R + o] = bng[o] * acc * inv + bnb[o];
}

// ---------------- Kernel 1b: depthwise diff + excite conv + gate + pos ----------------
__global__ __launch_bounds__(256) void k1b_xin(const float* __restrict__ x3, const float* __restrict__ dww,
                                               const float* __restrict__ exw, const float* __restrict__ x,
                                               const float* __restrict__ pos, float* __restrict__ xin) {
    __shared__ float sx3[10 * R];
    __shared__ float sxp[8 * R];
    int blk = blockIdx.x;               // 512 blocks
    int b = blk >> 7, t0 = (blk & 127) << 3;
    int tid = threadIdx.x;
    for (int e = tid; e < 320; e += 256) {
        int rr = e >> 5, o = e & 31;
        int tt = t0 + rr;
        sx3[e] = (tt < T) ? x3[(size_t)(b * T + tt) * R + o] : 0.f;
    }
    __syncthreads();
    {
        int rr = tid >> 5, o = tid & 31;
        int tt = t0 + rr;
        float v;
        if (tt == T - 1) {
            v = sx3[rr * R + o];
        } else {
            float w0 = dww[o * 3 + 0], w1 = dww[o * 3 + 1], w2 = dww[o * 3 + 2];
            v = sx3[rr * R + o] * (w0 - 1.f) + sx3[(rr + 1) * R + o] * w1 + sx3[(rr + 2) * R + o] * w2;
        }
        sxp[rr * R + o] = v;
    }
    __syncthreads();
    int rr = tid >> 5, c0 = tid & 31;
    int tt = t0 + rr;
    #pragma unroll
    for (int u = 0; u < 2; ++u) {
        int c = c0 + u * 32;
        const float* ew = exw + c * R;
        float g = 0.f;
        #pragma unroll
        for (int o = 0; o < R; ++o) g += ew[o] * sxp[rr * R + o];
        float sg = sigmoidf_(g);
        size_t idx = (size_t)(b * T + tt) * KDIM + c;
        xin[idx] = x[idx] * sg + pos[tt * KDIM + c];
    }
}

// ---------------- Kernel 2: q/k/v/l convs + silu + head-scramble store ----------------
// pseudo layout: n = b*8 + (tt>>7), p = ((tt&127)<<3)|(o&7), c = o>>3
__global__ __launch_bounds__(256) void k2_qkvl(const float* __restrict__ xin,
        const float* __restrict__ wq, const float* __restrict__ bq,
        const float* __restrict__ wk, const float* __restrict__ bk,
        const float* __restrict__ wv, const float* __restrict__ wl,
        bf16* __restrict__ qo, bf16* __restrict__ ko, bf16* __restrict__ vo, bf16* __restrict__ lo) {
    __shared__ float sx[16 * KDIM];
    int blk = blockIdx.x;               // 512 blocks
    int b = blk >> 7, p0 = (blk & 127) << 3;
    int tid = threadIdx.x;
    #pragma unroll
    for (int m = 0; m < 4; ++m) {
        int e = tid + 256 * m;
        int rr = e >> 6, c = e & 63;
        int tt = p0 - 8 + rr;
        sx[e] = (tt >= 0) ? xin[(size_t)(b * T + tt) * KDIM + c] : 0.f;
    }
    __syncthreads();
    const float inv_sg = 0.35355339059327373f; // 1/64^0.25
    for (int which = 0; which < 2; ++which) {
        const float* W = which ? wk : wq;
        const float* Bv = which ? bk : bq;
        bf16* Out = which ? ko : qo;
        #pragma unroll
        for (int oo = 0; oo < 2; ++oo) {
            int o = tid + oo * 256;
            float bias = Bv[o];
            float acc[8];
            #pragma unroll
            for (int p = 0; p < 8; ++p) acc[p] = bias;
            const float* wrow = W + (size_t)o * KDIM * 5;
            for (int i = 0; i < KDIM; ++i) {
                #pragma unroll
                for (int s = 0; s < 5; ++s) {
                    float w = wrow[i * 5 + s];
                    const float* xr = &sx[(2 * s) * KDIM + i];
                    #pragma unroll
                    for (int p = 0; p < 8; ++p) acc[p] += xr[p * KDIM] * w;
                }
            }
            int c = o >> 3, h = o & 7;
            #pragma unroll
            for (int p = 0; p < 8; ++p) {
                int tt = p0 + p;
                int n = b * NH + (tt >> 7);
                int pp = ((tt & 127) << 3) | h;
                Out[(size_t)(n * T + pp) * KDIM + c] = f2b(siluf_(acc[p]) * inv_sg);
            }
        }
    }
    for (int which = 0; which < 2; ++which) {
        const float* W = which ? wl : wv;
        bf16* Out = which ? lo : vo;
        #pragma unroll
        for (int oo = 0; oo < 2; ++oo) {
            int o = tid + oo * 256;
            const float* wrow = W + (size_t)o * KDIM;
            float acc[8];
            #pragma unroll
            for (int p = 0; p < 8; ++p) acc[p] = 0.f;
            for (int i = 0; i < KDIM; ++i) {
                float w = wrow[i];
                const float* xr = &sx[8 * KDIM + i];
                #pragma unroll
                for (int p = 0; p < 8; ++p) acc[p] += xr[p * KDIM] * w;
            }
            int c = o >> 3, h = o & 7;
            #pragma unroll
            for (int p = 0; p < 8; ++p) {
                int tt = p0 + p;
                int n = b * NH + (tt >> 7);
                int pp = ((tt & 127) << 3) | h;
                Out[(size_t)(n * T + pp) * KDIM + c] = f2b(siluf_(acc[p]));
            }
        }
    }
}

// ---------------- Kernel 3: local windowed causal attention (window 5) ----------------
__global__ __launch_bounds__(256) void k3_local(const bf16* __restrict__ lws, bf16* __restrict__ ol) {
    int wave = threadIdx.x >> 6, lane = threadIdx.x & 63;
    int ridx = blockIdx.x * 4 + wave;   // 8192 blocks -> 32768 rows
    int n = ridx >> 10, p = ridx & 1023;
    const bf16* base = lws + (size_t)n * T * KDIM;
    float lp = b2f(base[(size_t)p * KDIM + lane]);
    float lj[6], s[6];
    #pragma unroll
    for (int u = 0; u < 6; ++u) {
        int j = p - 5 + u;
        bool valid = (j >= 0);
        lj[u] = valid ? b2f(base[(size_t)j * KDIM + lane]) : 0.f;
        float d = lp * lj[u];
        d = waveSum64(d);
        s[u] = valid ? d * 0.125f : NEGBIG;
    }
    float mx = s[5];
    #pragma unroll
    for (int u = 0; u < 5; ++u) mx = fmaxf(mx, s[u]);
    float Z = 0.f, acc = 0.f;
    #pragma unroll
    for (int u = 0; u < 6; ++u) {
        float e = (s[u] <= NEGBIG) ? 0.f : __expf(s[u] - mx);
        Z += e;
        acc += e * lj[u];
    }
    ol[(size_t)(n * T + p) * KDIM + lane] = f2b(acc / Z);
}

// ---------------- Kernel 4 (MFMA): global causal flash attention ----------------
// Block = one (n, 64-row q-tile); 4 waves x 16 q-rows. og aliases q (in-place, safe:
// block's q rows staged to LDS before any og store; rows owned exclusively).
// MFMA layouts (HW-verified, learn_hip m89/m91/m120):
//   C/D: col = lane&15, row = (lane>>4)*4 + reg
//   A:   row m = lane&15, k = (lane>>4)*8 + j   (B symmetric: col n = lane&15)
__global__ __launch_bounds__(256) void k4_mfma(const bf16* __restrict__ qws, const bf16* __restrict__ kws,
                                               const bf16* __restrict__ vws, bf16* __restrict__ og) {
    typedef __attribute__((ext_vector_type(8))) short bf16x8s;
    typedef __attribute__((ext_vector_type(4))) short bf16x4s;
    typedef __attribute__((ext_vector_type(4))) float f32x4;
    __shared__ __align__(16) bf16 sQ[64][72];
    __shared__ __align__(16) bf16 sK[64][72];
    __shared__ __align__(16) bf16 sVt[64][72];   // sVt[c][j] = V[j0+j][c]
    __shared__ __align__(16) bf16 sPt[4][16][76]; // per-wave P^T: [m][j], pitch 76 vs conflicts

    int n = blockIdx.x >> 4, qt = blockIdx.x & 15;   // 512 blocks
    int p0 = qt << 6;
    int tid = threadIdx.x, w = tid >> 6, lane = tid & 63;
    int lm = lane & 15, quad = lane >> 4;

    const uint4* qg = (const uint4*)(qws + ((size_t)n * T + p0) * KDIM);
    #pragma unroll
    for (int r = 0; r < 2; ++r) { int e = tid + 256 * r; *(uint4*)&sQ[e >> 3][(e & 7) * 8] = qg[e]; }
    __syncthreads();

    bf16x8s aQ[2];
    #pragma unroll
    for (int ks = 0; ks < 2; ++ks) aQ[ks] = *(const bf16x8s*)&sQ[w * 16 + lm][ks * 32 + quad * 8];

    f32x4 O[4];
    float m_i[4], l_i[4];
    #pragma unroll
    for (int t = 0; t < 4; ++t) { O[t][0] = 0.f; O[t][1] = 0.f; O[t][2] = 0.f; O[t][3] = 0.f; }
    #pragma unroll
    for (int r4 = 0; r4 < 4; ++r4) { m_i[r4] = NEGBIG; l_i[r4] = 0.f; }

    for (int jt = 0; jt <= qt; ++jt) {
        int j0 = jt << 6;
        __syncthreads();   // prev iteration's sK/sVt readers done
        const uint4* kg = (const uint4*)(kws + ((size_t)n * T + j0) * KDIM);
        #pragma unroll
        for (int r = 0; r < 2; ++r) { int e = tid + 256 * r; *(uint4*)&sK[e >> 3][(e & 7) * 8] = kg[e]; }
        {
            const bf16* vgp = vws + ((size_t)n * T + j0) * KDIM;
            int j = tid & 63;
            #pragma unroll
            for (int hv = 0; hv < 2; ++hv) {
                int c0 = ((tid >> 6) + 4 * hv) * 8;
                uint4 raw = *(const uint4*)(vgp + (size_t)j * KDIM + c0);
                bf16 tmp[8];
                *(uint4*)tmp = raw;
                #pragma unroll
                for (int i = 0; i < 8; ++i) sVt[c0 + i][j] = tmp[i];
            }
        }
        __syncthreads();

        // ---- QK^T: 8 MFMA ----
        f32x4 S[4];
        #pragma unroll
        for (int nt = 0; nt < 4; ++nt) {
            f32x4 acc; acc[0] = 0.f; acc[1] = 0.f; acc[2] = 0.f; acc[3] = 0.f;
            #pragma unroll
            for (int ks = 0; ks < 2; ++ks) {
                bf16x8s bK = *(const bf16x8s*)&sK[nt * 16 + lm][ks * 32 + quad * 8];
                acc = __builtin_amdgcn_mfma_f32_16x16x32_bf16(aQ[ks], bK, acc, 0, 0, 0);
            }
            S[nt] = acc;
        }
        // ---- mask + online softmax (row m = quad*4+r, col j = j0+nt*16+lm) ----
        float mt[4];
        #pragma unroll
        for (int r4 = 0; r4 < 4; ++r4) mt[r4] = NEGBIG;
        int prow_base = p0 + w * 16 + quad * 4;
        #pragma unroll
        for (int nt = 0; nt < 4; ++nt) {
            int jcol = j0 + nt * 16 + lm;
            #pragma unroll
            for (int r4 = 0; r4 < 4; ++r4) {
                float s = (jcol <= prow_base + r4) ? S[nt][r4] : NEGBIG;
                S[nt][r4] = s;
                mt[r4] = fmaxf(mt[r4], s);
            }
        }
        #pragma unroll
        for (int r4 = 0; r4 < 4; ++r4) {
            float v = mt[r4];
            v = fmaxf(v, __shfl_xor(v, 1)); v = fmaxf(v, __shfl_xor(v, 2));
            v = fmaxf(v, __shfl_xor(v, 4)); v = fmaxf(v, __shfl_xor(v, 8));
            mt[r4] = v;
        }
        float alpha[4], ps[4];
        #pragma unroll
        for (int r4 = 0; r4 < 4; ++r4) {
            float mnew = fmaxf(m_i[r4], mt[r4]);
            alpha[r4] = __expf(m_i[r4] - mnew);
            m_i[r4] = mnew; ps[r4] = 0.f;
        }
        #pragma unroll
        for (int nt = 0; nt < 4; ++nt) {
            #pragma unroll
            for (int r4 = 0; r4 < 4; ++r4) {
                float p = (S[nt][r4] <= NEGBIG) ? 0.f : __expf(S[nt][r4] - m_i[r4]);
                ps[r4] += p;
                sPt[w][quad * 4 + r4][nt * 16 + lm] = f2b(p);
            }
        }
        #pragma unroll
        for (int r4 = 0; r4 < 4; ++r4) {
            float v = ps[r4];
            v += __shfl_xor(v, 1); v += __shfl_xor(v, 2);
            v += __shfl_xor(v, 4); v += __shfl_xor(v, 8);
            l_i[r4] = l_i[r4] * alpha[r4] + v;
        }
        #pragma unroll
        for (int t = 0; t < 4; ++t)
            #pragma unroll
            for (int r4 = 0; r4 < 4; ++r4) O[t][r4] *= alpha[r4];
        // ---- PV: up to 8 MFMA (diagonal tile skips provably-masked k-step) ----
        int ksmax = (jt == qt) ? (w >> 1) : 1;
        for (int ks = 0; ks <= ksmax; ++ks) {
            bf16x4s plo = *(const bf16x4s*)&sPt[w][lm][ks * 32 + quad * 8];
            bf16x4s phi = *(const bf16x4s*)&sPt[w][lm][ks * 32 + quad * 8 + 4];
            bf16x8s aP;
            #pragma unroll
            for (int i = 0; i < 4; ++i) { aP[i] = plo[i]; aP[i + 4] = phi[i]; }
            #pragma unroll
            for (int ct = 0; ct < 4; ++ct) {
                bf16x8s bV = *(const bf16x8s*)&sVt[ct * 16 + lm][ks * 32 + quad * 8];
                O[ct] = __builtin_amdgcn_mfma_f32_16x16x32_bf16(aP, bV, O[ct], 0, 0, 0);
            }
        }
    }
    // ---- epilogue ----
    #pragma unroll
    for (int r4 = 0; r4 < 4; ++r4) {
        int p = p0 + w * 16 + quad * 4 + r4;
        float inv = 1.f / l_i[r4];
        bf16* ob = og + ((size_t)n * T + p) * KDIM;
        #pragma unroll
        for (int t = 0; t < 4; ++t) ob[t * 16 + lm] = f2b(O[t][r4] * inv);
    }
}

// ---------------- Kernel 5: gate/concat + uni matmul + silu + residual + LN1 + FF + LN2 ----------------
__global__ __launch_bounds__(256) void k5_out(const bf16* __restrict__ og, const bf16* __restrict__ olw,
        const float* __restrict__ uniw, const float* __restrict__ unib, const float* __restrict__ xin,
        const float* __restrict__ ln1g, const float* __restrict__ ln1b,
        const float* __restrict__ ffw1, const float* __restrict__ ffb1,
        const float* __restrict__ ffw2, const float* __restrict__ ffb2,
        const float* __restrict__ ln2g, const float* __restrict__ ln2b,
        float* __restrict__ out) {
    __shared__ float su[1024];
    __shared__ float sr[256];
    __shared__ float sy[64];
    __shared__ float sh[256];
    int blk = blockIdx.x;               // 4096 blocks
    int b = blk >> 10, p = blk & 1023;
    int tid = threadIdx.x;
    #pragma unroll
    for (int m = 0; m < 4; ++m) {
        int d = tid + 256 * m;
        int hh = d >> 6, c = d & 63, hi = hh & 7;
        size_t idx = (size_t)((b * NH + hi) * T + p) * KDIM + c;
        float gv = b2f(og[idx]);
        float sg = sigmoidf_(gv);
        su[d] = (hh < 8) ? (1.f - sg) * b2f(olw[idx]) : sg * gv;
    }
    __syncthreads();
    int c = tid & 63, quarter = tid >> 6;
    float part = 0.f;
    for (int dd = 0; dd < 256; ++dd) {
        int d = quarter * 256 + dd;
        part += su[d] * uniw[(size_t)d * KDIM + c];
    }
    sr[tid] = part;
    __syncthreads();
    float y = 0.f;
    if (tid < 64) {
        float tot = sr[c] + sr[64 + c] + sr[128 + c] + sr[192 + c] + unib[c];
        float a = siluf_(tot);
        float yv = a + xin[(size_t)(b * T + p) * KDIM + c];
        float mean = waveSum64(yv) * (1.f / 64.f);
        float dv = yv - mean;
        float var = waveSum64(dv * dv) * (1.f / 64.f);
        y = dv * rsqrtf(var + 1e-5f) * ln1g[c] + ln1b[c];
        sy[c] = y;
    }
    __syncthreads();
    {
        int j = tid;
        float hv = ffb1[j];
        for (int i = 0; i < 64; ++i) hv += sy[i] * ffw1[i * 256 + j];
        sh[j] = fmaxf(hv, 0.f);
    }
    __syncthreads();
    if (tid < 64) {
        float f = ffb2[c];
        for (int j = 0; j < 256; ++j) f += sh[j] * ffw2[j * KDIM + c];
        float z = f + y;
        float mean = waveSum64(z) * (1.f / 64.f);
        float dv = z - mean;
        float var = waveSum64(dv * dv) * (1.f / 64.f);
        out[(size_t)(b * T + p) * KDIM + c] = dv * rsqrtf(var + 1e-5f) * ln2g[c] + ln2b[c];
    }
}

extern "C" void kernel_launch(void* const* d_in, const int* in_sizes, int n_in,
                              void* d_out, int out_size, void* d_ws, size_t ws_size,
                              hipStream_t stream) {
    (void)in_sizes; (void)n_in; (void)out_size; (void)ws_size;
    const float* x    = (const float*)d_in[0];
    const float* sqw  = (const float*)d_in[1];
    const float* bng  = (const float*)d_in[2];
    const float* bnb  = (const float*)d_in[3];
    const float* dww  = (const float*)d_in[4];
    const float* exw  = (const float*)d_in[5];
    const float* pos  = (const float*)d_in[6];
    const float* wq   = (const float*)d_in[7];
    const float* bq   = (const float*)d_in[8];
    const float* wk   = (const float*)d_in[9];
    const float* bk   = (const float*)d_in[10];
    const float* wv   = (const float*)d_in[11];
    const float* wl   = (const float*)d_in[12];
    const float* uniw = (const float*)d_in[13];
    const float* unib = (const float*)d_in[14];
    const float* ln1g = (const float*)d_in[15];
    const float* ln1b = (const float*)d_in[16];
    const float* ln2g = (const float*)d_in[17];
    const float* ln2b = (const float*)d_in[18];
    const float* ffw1 = (const float*)d_in[19];
    const float* ffb1 = (const float*)d_in[20];
    const float* ffw2 = (const float*)d_in[21];
    const float* ffb2 = (const float*)d_in[22];

    // ws layout — 21.5 MiB.
    char* ws = (char*)d_ws;
    float* xin = (float*)(ws);                    // fp32 1.0 MiB
    bf16*  qog = (bf16*)(ws + 0x100000);          // 4 MiB  q, then og in-place
    bf16*  kw_ = (bf16*)(ws + 0x500000);          // 4 MiB
    bf16*  vw_ = (bf16*)(ws + 0x900000);          // 4 MiB
    bf16*  lw_ = (bf16*)(ws + 0xD00000);          // 4 MiB
    bf16*  olw = (bf16*)(ws + 0x1100000);         // 4 MiB
    float* x3  = (float*)(ws + 0x1500000);        // fp32 0.5 MiB (end 0x1580000)

    k1a_x3 <<<512, 256, 0, stream>>>(x, sqw, bng, bnb, x3);
    k1b_xin<<<512, 256, 0, stream>>>(x3, dww, exw, x, pos, xin);
    k2_qkvl<<<512, 256, 0, stream>>>(xin, wq, bq, wk, bk, wv, wl, qog, kw_, vw_, lw_);
    k3_local<<<8192, 256, 0, stream>>>(lw_, olw);
    k4_mfma<<<512, 256, 0, stream>>>(qog, kw_, vw_, qog);   // og overwrites q in-place
    k5_out <<<4096, 256, 0, stream>>>(qog, olw, uniw, unib, xin,
                                      ln1g, ln1b, ffw1, ffb1, ffw2, ffb2, ln2g, ln2b,
                                      (float*)d_out);
}

// Round 9
// 262.857 us; speedup vs baseline: 26.9648x; 1.2941x over previous
//
#include <hip/hip_runtime.h>
#include <hip/hip_bf16.h>
#include <math.h>

#define B 4
#define T 1024
#define KDIM 64
#define R 32
#define NH 8
#define NEGBIG (-1e30f)

typedef __hip_bfloat16 bf16;
typedef __attribute__((ext_vector_type(8))) short bf16x8s;
typedef __attribute__((ext_vector_type(4))) short bf16x4s;
typedef __attribute__((ext_vector_type(4))) float f32x4;

static __device__ __forceinline__ float b2f(bf16 x) { return __bfloat162float(x); }
static __device__ __forceinline__ bf16 f2b(float x) { return __float2bfloat16(x); }
static __device__ __forceinline__ float sigmoidf_(float x) { return 1.0f / (1.0f + __expf(-x)); }
static __device__ __forceinline__ float siluf_(float x) { return x * sigmoidf_(x); }

static __device__ __forceinline__ float waveSum64(float v) {
    #pragma unroll
    for (int m = 32; m >= 1; m >>= 1) v += __shfl_xor(v, m);
    return v;
}

// ---------------- Kernel 1a: x3 = bn(squeeze conv)  +  fused weight prep ----------------
// Weight prep: BqT/BkT[o][s*64+i] = bf16(w[o][i*5+s]); BvT/BlT[o][i] = bf16(w[o][i]).
__global__ __launch_bounds__(256) void k1a_x3(const float* __restrict__ x, const float* __restrict__ sqw,
                                              const float* __restrict__ bng, const float* __restrict__ bnb,
                                              const float* __restrict__ wq, const float* __restrict__ wk,
                                              const float* __restrict__ wv, const float* __restrict__ wl,
                                              float* __restrict__ x3,
                                              bf16* __restrict__ BqT, bf16* __restrict__ BkT,
                                              bf16* __restrict__ BvT, bf16* __restrict__ BlT) {
    int blk = blockIdx.x;               // 512 blocks
    int b = blk >> 7, t0 = (blk & 127) << 3;
    int row = threadIdx.x >> 5, o = threadIdx.x & 31;
    int tt = t0 + row;
    const float* xr = x + (size_t)(b * T + tt) * KDIM;
    const float* wr = sqw + o * KDIM;
    float acc = 0.f;
    #pragma unroll
    for (int i = 0; i < KDIM; ++i) acc += xr[i] * wr[i];
    const float inv = 0.9999950000374997f; // 1/sqrt(1+1e-5)
    x3[(size_t)(b * T + tt) * R + o] = bng[o] * acc * inv + bnb[o];

    // fused weight conversion: 131072 threads x 3 elements = 393216
    int gid = blk * 256 + threadIdx.x;
    #pragma unroll
    for (int rep = 0; rep < 3; ++rep) {
        int e = gid + rep * 131072;
        if (e < 163840) {
            int oo = e / 320, kk = e - oo * 320;
            int s = kk >> 6, i = kk & 63;
            BqT[e] = f2b(wq[oo * 320 + i * 5 + s]);
        } else if (e < 327680) {
            int e2 = e - 163840;
            int oo = e2 / 320, kk = e2 - oo * 320;
            int s = kk >> 6, i = kk & 63;
            BkT[e2] = f2b(wk[oo * 320 + i * 5 + s]);
        } else if (e < 360448) {
            int e3 = e - 327680;
            BvT[e3] = f2b(wv[e3]);
        } else {
            int e4 = e - 360448;
            BlT[e4] = f2b(wl[e4]);
        }
    }
}

// ---------------- Kernel 1b: depthwise diff + excite conv + gate + pos ----------------
__global__ __launch_bounds__(256) void k1b_xin(const float* __restrict__ x3, const float* __restrict__ dww,
                                               const float* __restrict__ exw, const float* __restrict__ x,
                                               const float* __restrict__ pos, float* __restrict__ xin) {
    __shared__ float sx3[10 * R];
    __shared__ float sxp[8 * R];
    int blk = blockIdx.x;               // 512 blocks
    int b = blk >> 7, t0 = (blk & 127) << 3;
    int tid = threadIdx.x;
    for (int e = tid; e < 320; e += 256) {
        int rr = e >> 5, o = e & 31;
        int tt = t0 + rr;
        sx3[e] = (tt < T) ? x3[(size_t)(b * T + tt) * R + o] : 0.f;
    }
    __syncthreads();
    {
        int rr = tid >> 5, o = tid & 31;
        int tt = t0 + rr;
        float v;
        if (tt == T - 1) {
            v = sx3[rr * R + o];
        } else {
            float w0 = dww[o * 3 + 0], w1 = dww[o * 3 + 1], w2 = dww[o * 3 + 2];
            v = sx3[rr * R + o] * (w0 - 1.f) + sx3[(rr + 1) * R + o] * w1 + sx3[(rr + 2) * R + o] * w2;
        }
        sxp[rr * R + o] = v;
    }
    __syncthreads();
    int rr = tid >> 5, c0 = tid & 31;
    int tt = t0 + rr;
    #pragma unroll
    for (int u = 0; u < 2; ++u) {
        int c = c0 + u * 32;
        const float* ew = exw + c * R;
        float g = 0.f;
        #pragma unroll
        for (int o = 0; o < R; ++o) g += ew[o] * sxp[rr * R + o];
        float sg = sigmoidf_(g);
        size_t idx = (size_t)(b * T + tt) * KDIM + c;
        xin[idx] = x[idx] * sg + pos[tt * KDIM + c];
    }
}

// ---------------- Kernel 2 (MFMA): q/k/v/l convs + silu + head-scramble store ----------------
// GEMM view: out[t,o] = sum_{k} A[t,k] * Bw[k,o];  K reordered s-major (k = s*64+i) so each
// 32-wide k-step sits inside one tap s. sel 0: q+v, sel 1: k+l.
// scramble: n = b*8 + (tt>>7), pp = ((tt&127)<<3)|(o&7), c = o>>3
__global__ __launch_bounds__(256) void k2_mfma(const float* __restrict__ xin,
        const bf16* __restrict__ BqT, const bf16* __restrict__ BkT,
        const bf16* __restrict__ BvT, const bf16* __restrict__ BlT,
        const float* __restrict__ bq, const float* __restrict__ bk,
        bf16* __restrict__ qo, bf16* __restrict__ ko, bf16* __restrict__ vo, bf16* __restrict__ lo) {
    __shared__ __align__(16) bf16 sX[24][72];
    int blk = blockIdx.x;               // 512 blocks
    int sel = blk >> 8;                 // 0: q+v, 1: k+l
    int b = (blk >> 6) & 3, t0 = (blk & 63) << 4;
    int tid = threadIdx.x, w = tid >> 6, lane = tid & 63;
    int lm = lane & 15, quad = lane >> 4;

    for (int e = tid; e < 1536; e += 256) {
        int rr = e >> 6, ch = e & 63;
        int t = t0 - 8 + rr;
        sX[rr][ch] = f2b((t >= 0) ? xin[((size_t)(b * T) + t) * KDIM + ch] : 0.f);
    }
    __syncthreads();

    // A-fragments: row m=lm (timestep t0+lm), k-step ks -> tap s=ks>>1, i0=(ks&1)*32+quad*8.
    bf16x8s aX[10];
    #pragma unroll
    for (int ks = 0; ks < 10; ++ks)
        aX[ks] = *(const bf16x8s*)&sX[lm + 2 * (ks >> 1)][(ks & 1) * 32 + quad * 8];

    const bf16* Bd = sel ? BkT : BqT;
    const float* bias = sel ? bk : bq;
    const bf16* Bp = sel ? BlT : BvT;
    bf16* OutD = sel ? ko : qo;
    bf16* OutP = sel ? lo : vo;
    const float isg = 0.35355339059327373f; // 1/64^0.25

    // ---- dilated conv (q or k): K=320 ----
    for (int nt8 = 0; nt8 < 8; ++nt8) {
        int nt = w * 8 + nt8;
        int o = nt * 16 + lm;
        f32x4 acc = {0.f, 0.f, 0.f, 0.f};
        const bf16* br = Bd + (size_t)o * 320;
        #pragma unroll
        for (int ks = 0; ks < 10; ++ks) {
            bf16x8s bB = *(const bf16x8s*)&br[ks * 32 + quad * 8];
            acc = __builtin_amdgcn_mfma_f32_16x16x32_bf16(aX[ks], bB, acc, 0, 0, 0);
        }
        float bb = bias[o];
        int c = o >> 3, h = o & 7;
        #pragma unroll
        for (int r4 = 0; r4 < 4; ++r4) {
            int tt = t0 + quad * 4 + r4;
            int n = (b << 3) + (tt >> 7);
            int pp = ((tt & 127) << 3) | h;
            OutD[((size_t)n * T + pp) * KDIM + c] = f2b(siluf_(acc[r4] + bb) * isg);
        }
    }
    // ---- pointwise conv (v or l): K=64 (taps = rows t+0 -> aX[8], aX[9]) ----
    for (int nt8 = 0; nt8 < 8; ++nt8) {
        int nt = w * 8 + nt8;
        int o = nt * 16 + lm;
        f32x4 acc = {0.f, 0.f, 0.f, 0.f};
        const bf16* br = Bp + (size_t)o * 64;
        #pragma unroll
        for (int ks = 0; ks < 2; ++ks) {
            bf16x8s bB = *(const bf16x8s*)&br[ks * 32 + quad * 8];
            acc = __builtin_amdgcn_mfma_f32_16x16x32_bf16(aX[8 + ks], bB, acc, 0, 0, 0);
        }
        int c = o >> 3, h = o & 7;
        #pragma unroll
        for (int r4 = 0; r4 < 4; ++r4) {
            int tt = t0 + quad * 4 + r4;
            int n = (b << 3) + (tt >> 7);
            int pp = ((tt & 127) << 3) | h;
            OutP[((size_t)n * T + pp) * KDIM + c] = f2b(siluf_(acc[r4]));
        }
    }
}

// ---------------- Kernel 3: local windowed causal attention (window 5) ----------------
__global__ __launch_bounds__(256) void k3_local(const bf16* __restrict__ lws, bf16* __restrict__ ol) {
    int wave = threadIdx.x >> 6, lane = threadIdx.x & 63;
    int ridx = blockIdx.x * 4 + wave;   // 8192 blocks -> 32768 rows
    int n = ridx >> 10, p = ridx & 1023;
    const bf16* base = lws + (size_t)n * T * KDIM;
    float lp = b2f(base[(size_t)p * KDIM + lane]);
    float lj[6], s[6];
    #pragma unroll
    for (int u = 0; u < 6; ++u) {
        int j = p - 5 + u;
        bool valid = (j >= 0);
        lj[u] = valid ? b2f(base[(size_t)j * KDIM + lane]) : 0.f;
        float d = lp * lj[u];
        d = waveSum64(d);
        s[u] = valid ? d * 0.125f : NEGBIG;
    }
    float mx = s[5];
    #pragma unroll
    for (int u = 0; u < 5; ++u) mx = fmaxf(mx, s[u]);
    float Z = 0.f, acc = 0.f;
    #pragma unroll
    for (int u = 0; u < 6; ++u) {
        float e = (s[u] <= NEGBIG) ? 0.f : __expf(s[u] - mx);
        Z += e;
        acc += e * lj[u];
    }
    ol[(size_t)(n * T + p) * KDIM + lane] = f2b(acc / Z);
}

// ---------------- Kernel 4 (MFMA): global causal flash attention ----------------
__global__ __launch_bounds__(256) void k4_mfma(const bf16* __restrict__ qws, const bf16* __restrict__ kws,
                                               const bf16* __restrict__ vws, bf16* __restrict__ og) {
    __shared__ __align__(16) bf16 sQ[64][72];
    __shared__ __align__(16) bf16 sK[64][72];
    __shared__ __align__(16) bf16 sVt[64][72];   // sVt[c][j] = V[j0+j][c]
    __shared__ __align__(16) bf16 sPt[4][16][76];

    int n = blockIdx.x >> 4, qt = blockIdx.x & 15;   // 512 blocks
    int p0 = qt << 6;
    int tid = threadIdx.x, w = tid >> 6, lane = tid & 63;
    int lm = lane & 15, quad = lane >> 4;

    const uint4* qg = (const uint4*)(qws + ((size_t)n * T + p0) * KDIM);
    #pragma unroll
    for (int r = 0; r < 2; ++r) { int e = tid + 256 * r; *(uint4*)&sQ[e >> 3][(e & 7) * 8] = qg[e]; }
    __syncthreads();

    bf16x8s aQ[2];
    #pragma unroll
    for (int ks = 0; ks < 2; ++ks) aQ[ks] = *(const bf16x8s*)&sQ[w * 16 + lm][ks * 32 + quad * 8];

    f32x4 O[4];
    float m_i[4], l_i[4];
    #pragma unroll
    for (int t = 0; t < 4; ++t) { O[t][0] = 0.f; O[t][1] = 0.f; O[t][2] = 0.f; O[t][3] = 0.f; }
    #pragma unroll
    for (int r4 = 0; r4 < 4; ++r4) { m_i[r4] = NEGBIG; l_i[r4] = 0.f; }

    for (int jt = 0; jt <= qt; ++jt) {
        int j0 = jt << 6;
        __syncthreads();
        const uint4* kg = (const uint4*)(kws + ((size_t)n * T + j0) * KDIM);
        #pragma unroll
        for (int r = 0; r < 2; ++r) { int e = tid + 256 * r; *(uint4*)&sK[e >> 3][(e & 7) * 8] = kg[e]; }
        {
            const bf16* vgp = vws + ((size_t)n * T + j0) * KDIM;
            int j = tid & 63;
            #pragma unroll
            for (int hv = 0; hv < 2; ++hv) {
                int c0 = ((tid >> 6) + 4 * hv) * 8;
                uint4 raw = *(const uint4*)(vgp + (size_t)j * KDIM + c0);
                bf16 tmp[8];
                *(uint4*)tmp = raw;
                #pragma unroll
                for (int i = 0; i < 8; ++i) sVt[c0 + i][j] = tmp[i];
            }
        }
        __syncthreads();

        f32x4 S[4];
        #pragma unroll
        for (int nt = 0; nt < 4; ++nt) {
            f32x4 acc = {0.f, 0.f, 0.f, 0.f};
            #pragma unroll
            for (int ks = 0; ks < 2; ++ks) {
                bf16x8s bK = *(const bf16x8s*)&sK[nt * 16 + lm][ks * 32 + quad * 8];
                acc = __builtin_amdgcn_mfma_f32_16x16x32_bf16(aQ[ks], bK, acc, 0, 0, 0);
            }
            S[nt] = acc;
        }
        float mt[4];
        #pragma unroll
        for (int r4 = 0; r4 < 4; ++r4) mt[r4] = NEGBIG;
        int prow_base = p0 + w * 16 + quad * 4;
        #pragma unroll
        for (int nt = 0; nt < 4; ++nt) {
            int jcol = j0 + nt * 16 + lm;
            #pragma unroll
            for (int r4 = 0; r4 < 4; ++r4) {
                float s = (jcol <= prow_base + r4) ? S[nt][r4] : NEGBIG;
                S[nt][r4] = s;
                mt[r4] = fmaxf(mt[r4], s);
            }
        }
        #pragma unroll
        for (int r4 = 0; r4 < 4; ++r4) {
            float v = mt[r4];
            v = fmaxf(v, __shfl_xor(v, 1)); v = fmaxf(v, __shfl_xor(v, 2));
            v = fmaxf(v, __shfl_xor(v, 4)); v = fmaxf(v, __shfl_xor(v, 8));
            mt[r4] = v;
        }
        float alpha[4], ps[4];
        #pragma unroll
        for (int r4 = 0; r4 < 4; ++r4) {
            float mnew = fmaxf(m_i[r4], mt[r4]);
            alpha[r4] = __expf(m_i[r4] - mnew);
            m_i[r4] = mnew; ps[r4] = 0.f;
        }
        #pragma unroll
        for (int nt = 0; nt < 4; ++nt) {
            #pragma unroll
            for (int r4 = 0; r4 < 4; ++r4) {
                float p = (S[nt][r4] <= NEGBIG) ? 0.f : __expf(S[nt][r4] - m_i[r4]);
                ps[r4] += p;
                sPt[w][quad * 4 + r4][nt * 16 + lm] = f2b(p);
            }
        }
        #pragma unroll
        for (int r4 = 0; r4 < 4; ++r4) {
            float v = ps[r4];
            v += __shfl_xor(v, 1); v += __shfl_xor(v, 2);
            v += __shfl_xor(v, 4); v += __shfl_xor(v, 8);
            l_i[r4] = l_i[r4] * alpha[r4] + v;
        }
        #pragma unroll
        for (int t = 0; t < 4; ++t)
            #pragma unroll
            for (int r4 = 0; r4 < 4; ++r4) O[t][r4] *= alpha[r4];
        int ksmax = (jt == qt) ? (w >> 1) : 1;
        for (int ks = 0; ks <= ksmax; ++ks) {
            bf16x4s plo = *(const bf16x4s*)&sPt[w][lm][ks * 32 + quad * 8];
            bf16x4s phi = *(const bf16x4s*)&sPt[w][lm][ks * 32 + quad * 8 + 4];
            bf16x8s aP;
            #pragma unroll
            for (int i = 0; i < 4; ++i) { aP[i] = plo[i]; aP[i + 4] = phi[i]; }
            #pragma unroll
            for (int ct = 0; ct < 4; ++ct) {
                bf16x8s bV = *(const bf16x8s*)&sVt[ct * 16 + lm][ks * 32 + quad * 8];
                O[ct] = __builtin_amdgcn_mfma_f32_16x16x32_bf16(aP, bV, O[ct], 0, 0, 0);
            }
        }
    }
    #pragma unroll
    for (int r4 = 0; r4 < 4; ++r4) {
        int p = p0 + w * 16 + quad * 4 + r4;
        float inv = 1.f / l_i[r4];
        bf16* ob = og + ((size_t)n * T + p) * KDIM;
        #pragma unroll
        for (int t = 0; t < 4; ++t) ob[t * 16 + lm] = f2b(O[t][r4] * inv);
    }
}

// ---------------- Kernel 5: gate/concat + uni matmul + silu + residual + LN1 + FF + LN2 ----------------
__global__ __launch_bounds__(256) void k5_out(const bf16* __restrict__ og, const bf16* __restrict__ olw,
        const float* __restrict__ uniw, const float* __restrict__ unib, const float* __restrict__ xin,
        const float* __restrict__ ln1g, const float* __restrict__ ln1b,
        const float* __restrict__ ffw1, const float* __restrict__ ffb1,
        const float* __restrict__ ffw2, const float* __restrict__ ffb2,
        const float* __restrict__ ln2g, const float* __restrict__ ln2b,
        float* __restrict__ out) {
    __shared__ float su[1024];
    __shared__ float sr[256];
    __shared__ float sy[64];
    __shared__ float sh[256];
    int blk = blockIdx.x;               // 4096 blocks
    int b = blk >> 10, p = blk & 1023;
    int tid = threadIdx.x;
    #pragma unroll
    for (int m = 0; m < 4; ++m) {
        int d = tid + 256 * m;
        int hh = d >> 6, c = d & 63, hi = hh & 7;
        size_t idx = (size_t)((b * NH + hi) * T + p) * KDIM + c;
        float gv = b2f(og[idx]);
        float sg = sigmoidf_(gv);
        su[d] = (hh < 8) ? (1.f - sg) * b2f(olw[idx]) : sg * gv;
    }
    __syncthreads();
    int c = tid & 63, quarter = tid >> 6;
    float part = 0.f;
    for (int dd = 0; dd < 256; ++dd) {
        int d = quarter * 256 + dd;
        part += su[d] * uniw[(size_t)d * KDIM + c];
    }
    sr[tid] = part;
    __syncthreads();
    float y = 0.f;
    if (tid < 64) {
        float tot = sr[c] + sr[64 + c] + sr[128 + c] + sr[192 + c] + unib[c];
        float a = siluf_(tot);
        float yv = a + xin[(size_t)(b * T + p) * KDIM + c];
        float mean = waveSum64(yv) * (1.f / 64.f);
        float dv = yv - mean;
        float var = waveSum64(dv * dv) * (1.f / 64.f);
        y = dv * rsqrtf(var + 1e-5f) * ln1g[c] + ln1b[c];
        sy[c] = y;
    }
    __syncthreads();
    {
        int j = tid;
        float hv = ffb1[j];
        for (int i = 0; i < 64; ++i) hv += sy[i] * ffw1[i * 256 + j];
        sh[j] = fmaxf(hv, 0.f);
    }
    __syncthreads();
    if (tid < 64) {
        float f = ffb2[c];
        for (int j = 0; j < 256; ++j) f += sh[j] * ffw2[j * KDIM + c];
        float z = f + y;
        float mean = waveSum64(z) * (1.f / 64.f);
        float dv = z - mean;
        float var = waveSum64(dv * dv) * (1.f / 64.f);
        out[(size_t)(b * T + p) * KDIM + c] = dv * rsqrtf(var + 1e-5f) * ln2g[c] + ln2b[c];
    }
}

extern "C" void kernel_launch(void* const* d_in, const int* in_sizes, int n_in,
                              void* d_out, int out_size, void* d_ws, size_t ws_size,
                              hipStream_t stream) {
    (void)in_sizes; (void)n_in; (void)out_size; (void)ws_size;
    const float* x    = (const float*)d_in[0];
    const float* sqw  = (const float*)d_in[1];
    const float* bng  = (const float*)d_in[2];
    const float* bnb  = (const float*)d_in[3];
    const float* dww  = (const float*)d_in[4];
    const float* exw  = (const float*)d_in[5];
    const float* pos  = (const float*)d_in[6];
    const float* wq   = (const float*)d_in[7];
    const float* bq   = (const float*)d_in[8];
    const float* wk   = (const float*)d_in[9];
    const float* bk   = (const float*)d_in[10];
    const float* wv   = (const float*)d_in[11];
    const float* wl   = (const float*)d_in[12];
    const float* uniw = (const float*)d_in[13];
    const float* unib = (const float*)d_in[14];
    const float* ln1g = (const float*)d_in[15];
    const float* ln1b = (const float*)d_in[16];
    const float* ln2g = (const float*)d_in[17];
    const float* ln2b = (const float*)d_in[18];
    const float* ffw1 = (const float*)d_in[19];
    const float* ffb1 = (const float*)d_in[20];
    const float* ffw2 = (const float*)d_in[21];
    const float* ffb2 = (const float*)d_in[22];

    // ws layout — 22.25 MiB.
    char* ws = (char*)d_ws;
    float* xin = (float*)(ws);                    // fp32 1.0 MiB
    bf16*  qog = (bf16*)(ws + 0x100000);          // 4 MiB  q, then og in-place
    bf16*  kw_ = (bf16*)(ws + 0x500000);          // 4 MiB
    bf16*  vw_ = (bf16*)(ws + 0x900000);          // 4 MiB
    bf16*  lw_ = (bf16*)(ws + 0xD00000);          // 4 MiB
    bf16*  olw = (bf16*)(ws + 0x1100000);         // 4 MiB
    float* x3  = (float*)(ws + 0x1500000);        // fp32 0.5 MiB
    bf16*  BqT = (bf16*)(ws + 0x1580000);         // 320 KiB
    bf16*  BkT = (bf16*)(ws + 0x15D0000);         // 320 KiB
    bf16*  BvT = (bf16*)(ws + 0x1620000);         // 64 KiB
    bf16*  BlT = (bf16*)(ws + 0x1630000);         // 64 KiB (end 0x1640000)

    k1a_x3 <<<512, 256, 0, stream>>>(x, sqw, bng, bnb, wq, wk, wv, wl, x3, BqT, BkT, BvT, BlT);
    k1b_xin<<<512, 256, 0, stream>>>(x3, dww, exw, x, pos, xin);
    k2_mfma<<<512, 256, 0, stream>>>(xin, BqT, BkT, BvT, BlT, bq, bk, qog, kw_, vw_, lw_);
    k3_local<<<8192, 256, 0, stream>>>(lw_, olw);
    k4_mfma<<<512, 256, 0, stream>>>(qog, kw_, vw_, qog);   // og overwrites q in-place
    k5_out <<<4096, 256, 0, stream>>>(qog, olw, uniw, unib, xin,
                                      ln1g, ln1b, ffw1, ffb1, ffw2, ffb2, ln2g, ln2b,
                                      (float*)d_out);
}

// Round 10
// 246.085 us; speedup vs baseline: 28.8027x; 1.0682x over previous
//
#include <hip/hip_runtime.h>
#include <hip/hip_bf16.h>
#include <math.h>

#define B 4
#define T 1024
#define KDIM 64
#define R 32
#define NH 8
#define NEGBIG (-1e30f)

typedef __hip_bfloat16 bf16;
typedef __attribute__((ext_vector_type(8))) short bf16x8s;
typedef __attribute__((ext_vector_type(4))) short bf16x4s;
typedef __attribute__((ext_vector_type(4))) float f32x4;

static __device__ __forceinline__ float b2f(bf16 x) { return __bfloat162float(x); }
static __device__ __forceinline__ bf16 f2b(float x) { return __float2bfloat16(x); }
static __device__ __forceinline__ float sigmoidf_(float x) { return 1.0f / (1.0f + __expf(-x)); }
static __device__ __forceinline__ float siluf_(float x) { return x * sigmoidf_(x); }

static __device__ __forceinline__ float waveSum64(float v) {
    #pragma unroll
    for (int m = 32; m >= 1; m >>= 1) v += __shfl_xor(v, m);
    return v;
}

// ---------------- Kernel 1a: x3 = bn(squeeze conv)  +  fused weight prep ----------------
__global__ __launch_bounds__(256) void k1a_x3(const float* __restrict__ x, const float* __restrict__ sqw,
                                              const float* __restrict__ bng, const float* __restrict__ bnb,
                                              const float* __restrict__ wq, const float* __restrict__ wk,
                                              const float* __restrict__ wv, const float* __restrict__ wl,
                                              const float* __restrict__ uniw, const float* __restrict__ ffw1,
                                              const float* __restrict__ ffw2,
                                              float* __restrict__ x3,
                                              bf16* __restrict__ BqT, bf16* __restrict__ BkT,
                                              bf16* __restrict__ BvT, bf16* __restrict__ BlT,
                                              bf16* __restrict__ uniwT, bf16* __restrict__ ffw1T,
                                              bf16* __restrict__ ffw2T) {
    int blk = blockIdx.x;               // 512 blocks
    int b = blk >> 7, t0 = (blk & 127) << 3;
    int row = threadIdx.x >> 5, o = threadIdx.x & 31;
    int tt = t0 + row;
    const float* xr = x + (size_t)(b * T + tt) * KDIM;
    const float* wr = sqw + o * KDIM;
    float acc = 0.f;
    #pragma unroll
    for (int i = 0; i < KDIM; ++i) acc += xr[i] * wr[i];
    const float inv = 0.9999950000374997f; // 1/sqrt(1+1e-5)
    x3[(size_t)(b * T + tt) * R + o] = bng[o] * acc * inv + bnb[o];

    // fused conv-weight conversion (s-major K): 131072 threads x 3 = 393216
    int gid = blk * 256 + threadIdx.x;
    #pragma unroll
    for (int rep = 0; rep < 3; ++rep) {
        int e = gid + rep * 131072;
        if (e < 163840) {
            int oo = e / 320, kk = e - oo * 320;
            int s = kk >> 6, i = kk & 63;
            BqT[e] = f2b(wq[oo * 320 + i * 5 + s]);
        } else if (e < 327680) {
            int e2 = e - 163840;
            int oo = e2 / 320, kk = e2 - oo * 320;
            int s = kk >> 6, i = kk & 63;
            BkT[e2] = f2b(wk[oo * 320 + i * 5 + s]);
        } else if (e < 360448) {
            int e3 = e - 327680;
            BvT[e3] = f2b(wv[e3]);
        } else {
            int e4 = e - 360448;
            BlT[e4] = f2b(wl[e4]);
        }
    }
    // fused epilogue-weight transpose (bf16): uniwT[c][d], ffw1T[j][i], ffw2T[c][j]
    {
        int e = gid;
        if (e < 65536) {
            int c = e >> 10, d = e & 1023;
            uniwT[e] = f2b(uniw[d * 64 + c]);
        } else if (e < 81920) {
            int e2 = e - 65536;
            int j = e2 >> 6, i = e2 & 63;
            ffw1T[e2] = f2b(ffw1[i * 256 + j]);
        } else if (e < 98304) {
            int e3 = e - 81920;
            int c = e3 >> 8, j = e3 & 255;
            ffw2T[e3] = f2b(ffw2[j * 64 + c]);
        }
    }
}

// ---------------- Kernel 1b: depthwise diff + excite conv + gate + pos ----------------
__global__ __launch_bounds__(256) void k1b_xin(const float* __restrict__ x3, const float* __restrict__ dww,
                                               const float* __restrict__ exw, const float* __restrict__ x,
                                               const float* __restrict__ pos, float* __restrict__ xin) {
    __shared__ float sx3[10 * R];
    __shared__ float sxp[8 * R];
    int blk = blockIdx.x;               // 512 blocks
    int b = blk >> 7, t0 = (blk & 127) << 3;
    int tid = threadIdx.x;
    for (int e = tid; e < 320; e += 256) {
        int rr = e >> 5, o = e & 31;
        int tt = t0 + rr;
        sx3[e] = (tt < T) ? x3[(size_t)(b * T + tt) * R + o] : 0.f;
    }
    __syncthreads();
    {
        int rr = tid >> 5, o = tid & 31;
        int tt = t0 + rr;
        float v;
        if (tt == T - 1) {
            v = sx3[rr * R + o];
        } else {
            float w0 = dww[o * 3 + 0], w1 = dww[o * 3 + 1], w2 = dww[o * 3 + 2];
            v = sx3[rr * R + o] * (w0 - 1.f) + sx3[(rr + 1) * R + o] * w1 + sx3[(rr + 2) * R + o] * w2;
        }
        sxp[rr * R + o] = v;
    }
    __syncthreads();
    int rr = tid >> 5, c0 = tid & 31;
    int tt = t0 + rr;
    #pragma unroll
    for (int u = 0; u < 2; ++u) {
        int c = c0 + u * 32;
        const float* ew = exw + c * R;
        float g = 0.f;
        #pragma unroll
        for (int o = 0; o < R; ++o) g += ew[o] * sxp[rr * R + o];
        float sg = sigmoidf_(g);
        size_t idx = (size_t)(b * T + tt) * KDIM + c;
        xin[idx] = x[idx] * sg + pos[tt * KDIM + c];
    }
}

// ---------------- Kernel 2 (MFMA): q/k/v/l convs + silu + head-scramble store ----------------
__global__ __launch_bounds__(256) void k2_mfma(const float* __restrict__ xin,
        const bf16* __restrict__ BqT, const bf16* __restrict__ BkT,
        const bf16* __restrict__ BvT, const bf16* __restrict__ BlT,
        const float* __restrict__ bq, const float* __restrict__ bk,
        bf16* __restrict__ qo, bf16* __restrict__ ko, bf16* __restrict__ vo, bf16* __restrict__ lo) {
    __shared__ __align__(16) bf16 sX[24][72];
    int blk = blockIdx.x;               // 512 blocks
    int sel = blk >> 8;                 // 0: q+v, 1: k+l
    int b = (blk >> 6) & 3, t0 = (blk & 63) << 4;
    int tid = threadIdx.x, w = tid >> 6, lane = tid & 63;
    int lm = lane & 15, quad = lane >> 4;

    for (int e = tid; e < 1536; e += 256) {
        int rr = e >> 6, ch = e & 63;
        int t = t0 - 8 + rr;
        sX[rr][ch] = f2b((t >= 0) ? xin[((size_t)(b * T) + t) * KDIM + ch] : 0.f);
    }
    __syncthreads();

    bf16x8s aX[10];
    #pragma unroll
    for (int ks = 0; ks < 10; ++ks)
        aX[ks] = *(const bf16x8s*)&sX[lm + 2 * (ks >> 1)][(ks & 1) * 32 + quad * 8];

    const bf16* Bd = sel ? BkT : BqT;
    const float* bias = sel ? bk : bq;
    const bf16* Bp = sel ? BlT : BvT;
    bf16* OutD = sel ? ko : qo;
    bf16* OutP = sel ? lo : vo;
    const float isg = 0.35355339059327373f; // 1/64^0.25

    for (int nt8 = 0; nt8 < 8; ++nt8) {
        int nt = w * 8 + nt8;
        int o = nt * 16 + lm;
        f32x4 acc = {0.f, 0.f, 0.f, 0.f};
        const bf16* br = Bd + (size_t)o * 320;
        #pragma unroll
        for (int ks = 0; ks < 10; ++ks) {
            bf16x8s bB = *(const bf16x8s*)&br[ks * 32 + quad * 8];
            acc = __builtin_amdgcn_mfma_f32_16x16x32_bf16(aX[ks], bB, acc, 0, 0, 0);
        }
        float bb = bias[o];
        int c = o >> 3, h = o & 7;
        #pragma unroll
        for (int r4 = 0; r4 < 4; ++r4) {
            int tt = t0 + quad * 4 + r4;
            int n = (b << 3) + (tt >> 7);
            int pp = ((tt & 127) << 3) | h;
            OutD[((size_t)n * T + pp) * KDIM + c] = f2b(siluf_(acc[r4] + bb) * isg);
        }
    }
    for (int nt8 = 0; nt8 < 8; ++nt8) {
        int nt = w * 8 + nt8;
        int o = nt * 16 + lm;
        f32x4 acc = {0.f, 0.f, 0.f, 0.f};
        const bf16* br = Bp + (size_t)o * 64;
        #pragma unroll
        for (int ks = 0; ks < 2; ++ks) {
            bf16x8s bB = *(const bf16x8s*)&br[ks * 32 + quad * 8];
            acc = __builtin_amdgcn_mfma_f32_16x16x32_bf16(aX[8 + ks], bB, acc, 0, 0, 0);
        }
        int c = o >> 3, h = o & 7;
        #pragma unroll
        for (int r4 = 0; r4 < 4; ++r4) {
            int tt = t0 + quad * 4 + r4;
            int n = (b << 3) + (tt >> 7);
            int pp = ((tt & 127) << 3) | h;
            OutP[((size_t)n * T + pp) * KDIM + c] = f2b(siluf_(acc[r4]));
        }
    }
}

// ---------------- Kernel 3: local windowed causal attention (window 5) ----------------
__global__ __launch_bounds__(256) void k3_local(const bf16* __restrict__ lws, bf16* __restrict__ ol) {
    int wave = threadIdx.x >> 6, lane = threadIdx.x & 63;
    int ridx = blockIdx.x * 4 + wave;   // 8192 blocks -> 32768 rows
    int n = ridx >> 10, p = ridx & 1023;
    const bf16* base = lws + (size_t)n * T * KDIM;
    float lp = b2f(base[(size_t)p * KDIM + lane]);
    float lj[6], s[6];
    #pragma unroll
    for (int u = 0; u < 6; ++u) {
        int j = p - 5 + u;
        bool valid = (j >= 0);
        lj[u] = valid ? b2f(base[(size_t)j * KDIM + lane]) : 0.f;
        float d = lp * lj[u];
        d = waveSum64(d);
        s[u] = valid ? d * 0.125f : NEGBIG;
    }
    float mx = s[5];
    #pragma unroll
    for (int u = 0; u < 5; ++u) mx = fmaxf(mx, s[u]);
    float Z = 0.f, acc = 0.f;
    #pragma unroll
    for (int u = 0; u < 6; ++u) {
        float e = (s[u] <= NEGBIG) ? 0.f : __expf(s[u] - mx);
        Z += e;
        acc += e * lj[u];
    }
    ol[(size_t)(n * T + p) * KDIM + lane] = f2b(acc / Z);
}

// ---------------- Kernel 4 (MFMA): global causal flash attention ----------------
__global__ __launch_bounds__(256) void k4_mfma(const bf16* __restrict__ qws, const bf16* __restrict__ kws,
                                               const bf16* __restrict__ vws, bf16* __restrict__ og) {
    __shared__ __align__(16) bf16 sQ[64][72];
    __shared__ __align__(16) bf16 sK[64][72];
    __shared__ __align__(16) bf16 sVt[64][72];
    __shared__ __align__(16) bf16 sPt[4][16][76];

    int n = blockIdx.x >> 4, qt = blockIdx.x & 15;   // 512 blocks
    int p0 = qt << 6;
    int tid = threadIdx.x, w = tid >> 6, lane = tid & 63;
    int lm = lane & 15, quad = lane >> 4;

    const uint4* qg = (const uint4*)(qws + ((size_t)n * T + p0) * KDIM);
    #pragma unroll
    for (int r = 0; r < 2; ++r) { int e = tid + 256 * r; *(uint4*)&sQ[e >> 3][(e & 7) * 8] = qg[e]; }
    __syncthreads();

    bf16x8s aQ[2];
    #pragma unroll
    for (int ks = 0; ks < 2; ++ks) aQ[ks] = *(const bf16x8s*)&sQ[w * 16 + lm][ks * 32 + quad * 8];

    f32x4 O[4];
    float m_i[4], l_i[4];
    #pragma unroll
    for (int t = 0; t < 4; ++t) { O[t][0] = 0.f; O[t][1] = 0.f; O[t][2] = 0.f; O[t][3] = 0.f; }
    #pragma unroll
    for (int r4 = 0; r4 < 4; ++r4) { m_i[r4] = NEGBIG; l_i[r4] = 0.f; }

    for (int jt = 0; jt <= qt; ++jt) {
        int j0 = jt << 6;
        __syncthreads();
        const uint4* kg = (const uint4*)(kws + ((size_t)n * T + j0) * KDIM);
        #pragma unroll
        for (int r = 0; r < 2; ++r) { int e = tid + 256 * r; *(uint4*)&sK[e >> 3][(e & 7) * 8] = kg[e]; }
        {
            const bf16* vgp = vws + ((size_t)n * T + j0) * KDIM;
            int j = tid & 63;
            #pragma unroll
            for (int hv = 0; hv < 2; ++hv) {
                int c0 = ((tid >> 6) + 4 * hv) * 8;
                uint4 raw = *(const uint4*)(vgp + (size_t)j * KDIM + c0);
                bf16 tmp[8];
                *(uint4*)tmp = raw;
                #pragma unroll
                for (int i = 0; i < 8; ++i) sVt[c0 + i][j] = tmp[i];
            }
        }
        __syncthreads();

        f32x4 S[4];
        #pragma unroll
        for (int nt = 0; nt < 4; ++nt) {
            f32x4 acc = {0.f, 0.f, 0.f, 0.f};
            #pragma unroll
            for (int ks = 0; ks < 2; ++ks) {
                bf16x8s bK = *(const bf16x8s*)&sK[nt * 16 + lm][ks * 32 + quad * 8];
                acc = __builtin_amdgcn_mfma_f32_16x16x32_bf16(aQ[ks], bK, acc, 0, 0, 0);
            }
            S[nt] = acc;
        }
        float mt[4];
        #pragma unroll
        for (int r4 = 0; r4 < 4; ++r4) mt[r4] = NEGBIG;
        int prow_base = p0 + w * 16 + quad * 4;
        #pragma unroll
        for (int nt = 0; nt < 4; ++nt) {
            int jcol = j0 + nt * 16 + lm;
            #pragma unroll
            for (int r4 = 0; r4 < 4; ++r4) {
                float s = (jcol <= prow_base + r4) ? S[nt][r4] : NEGBIG;
                S[nt][r4] = s;
                mt[r4] = fmaxf(mt[r4], s);
            }
        }
        #pragma unroll
        for (int r4 = 0; r4 < 4; ++r4) {
            float v = mt[r4];
            v = fmaxf(v, __shfl_xor(v, 1)); v = fmaxf(v, __shfl_xor(v, 2));
            v = fmaxf(v, __shfl_xor(v, 4)); v = fmaxf(v, __shfl_xor(v, 8));
            mt[r4] = v;
        }
        float alpha[4], ps[4];
        #pragma unroll
        for (int r4 = 0; r4 < 4; ++r4) {
            float mnew = fmaxf(m_i[r4], mt[r4]);
            alpha[r4] = __expf(m_i[r4] - mnew);
            m_i[r4] = mnew; ps[r4] = 0.f;
        }
        #pragma unroll
        for (int nt = 0; nt < 4; ++nt) {
            #pragma unroll
            for (int r4 = 0; r4 < 4; ++r4) {
                float p = (S[nt][r4] <= NEGBIG) ? 0.f : __expf(S[nt][r4] - m_i[r4]);
                ps[r4] += p;
                sPt[w][quad * 4 + r4][nt * 16 + lm] = f2b(p);
            }
        }
        #pragma unroll
        for (int r4 = 0; r4 < 4; ++r4) {
            float v = ps[r4];
            v += __shfl_xor(v, 1); v += __shfl_xor(v, 2);
            v += __shfl_xor(v, 4); v += __shfl_xor(v, 8);
            l_i[r4] = l_i[r4] * alpha[r4] + v;
        }
        #pragma unroll
        for (int t = 0; t < 4; ++t)
            #pragma unroll
            for (int r4 = 0; r4 < 4; ++r4) O[t][r4] *= alpha[r4];
        int ksmax = (jt == qt) ? (w >> 1) : 1;
        for (int ks = 0; ks <= ksmax; ++ks) {
            bf16x4s plo = *(const bf16x4s*)&sPt[w][lm][ks * 32 + quad * 8];
            bf16x4s phi = *(const bf16x4s*)&sPt[w][lm][ks * 32 + quad * 8 + 4];
            bf16x8s aP;
            #pragma unroll
            for (int i = 0; i < 4; ++i) { aP[i] = plo[i]; aP[i + 4] = phi[i]; }
            #pragma unroll
            for (int ct = 0; ct < 4; ++ct) {
                bf16x8s bV = *(const bf16x8s*)&sVt[ct * 16 + lm][ks * 32 + quad * 8];
                O[ct] = __builtin_amdgcn_mfma_f32_16x16x32_bf16(aP, bV, O[ct], 0, 0, 0);
            }
        }
    }
    #pragma unroll
    for (int r4 = 0; r4 < 4; ++r4) {
        int p = p0 + w * 16 + quad * 4 + r4;
        float inv = 1.f / l_i[r4];
        bf16* ob = og + ((size_t)n * T + p) * KDIM;
        #pragma unroll
        for (int t = 0; t < 4; ++t) ob[t * 16 + lm] = f2b(O[t][r4] * inv);
    }
}

// ---------------- Kernel 5 (MFMA): gate/concat + uni GEMM + LN1 + FF + LN2 ----------------
// Block = 16 t-rows. uni: M16 K1024 N64; FF1: M16 K64 N256; FF2: M16 K256 N64.
__global__ __launch_bounds__(256) void k5_mfma(const bf16* __restrict__ og, const bf16* __restrict__ olw,
        const bf16* __restrict__ uniwT, const float* __restrict__ unib, const float* __restrict__ xin,
        const float* __restrict__ ln1g, const float* __restrict__ ln1b,
        const bf16* __restrict__ ffw1T, const float* __restrict__ ffb1,
        const bf16* __restrict__ ffw2T, const float* __restrict__ ffb2,
        const float* __restrict__ ln2g, const float* __restrict__ ln2b,
        float* __restrict__ out) {
    __shared__ __align__(16) bf16 sU[16][1032];  // gated concat, A of uni
    __shared__ float sY[16][68];                 // y fp32 (residual); later z in-place
    __shared__ __align__(16) bf16 sYb[16][72];   // ln1(y) bf16, A of FF1
    __shared__ __align__(16) bf16 sH[16][264];   // relu(h) bf16, A of FF2
    int blk = blockIdx.x;               // 256 blocks
    int b = blk >> 6, t0 = (blk & 63) << 4;
    int tid = threadIdx.x, w = tid >> 6, lane = tid & 63;
    int lm = lane & 15, quad = lane >> 4;

    // ---- stage gated concat su[row][d], d = hh*64+c ----
    for (int e = tid; e < 16384; e += 256) {
        int r = e >> 10, d = e & 1023;
        int hh = d >> 6, c = d & 63, hi = hh & 7;
        size_t idx = ((size_t)((b * NH + hi) * T) + t0 + r) * KDIM + c;
        float gv = b2f(og[idx]);
        float sg = sigmoidf_(gv);
        sU[r][d] = f2b((hh < 8) ? (1.f - sg) * b2f(olw[idx]) : sg * gv);
    }
    __syncthreads();

    // ---- uni GEMM: wave w owns cols w*16..+15 ----
    int col = w * 16 + lm;
    f32x4 accU = {0.f, 0.f, 0.f, 0.f};
    const bf16* ur = uniwT + (size_t)col * 1024;
    #pragma unroll
    for (int ks = 0; ks < 32; ++ks) {
        bf16x8s aU = *(const bf16x8s*)&sU[lm][ks * 32 + quad * 8];
        bf16x8s bU = *(const bf16x8s*)&ur[ks * 32 + quad * 8];
        accU = __builtin_amdgcn_mfma_f32_16x16x32_bf16(aU, bU, accU, 0, 0, 0);
    }
    float ub = unib[col];
    #pragma unroll
    for (int r4 = 0; r4 < 4; ++r4) {
        int row = quad * 4 + r4;
        float a = siluf_(accU[r4] + ub);
        sY[row][col] = a + xin[((size_t)(b * T) + t0 + row) * KDIM + col];
    }
    __syncthreads();

    // ---- LN1 (wave w handles rows w, w+4, w+8, w+12) ----
    #pragma unroll
    for (int i = 0; i < 4; ++i) {
        int row = w + 4 * i;
        float yv = sY[row][lane];
        float mean = waveSum64(yv) * (1.f / 64.f);
        float dv = yv - mean;
        float var = waveSum64(dv * dv) * (1.f / 64.f);
        float y = dv * rsqrtf(var + 1e-5f) * ln1g[lane] + ln1b[lane];
        sY[row][lane] = y;            // fp32 y for residual
        sYb[row][lane] = f2b(y);      // bf16 A for FF1
    }
    __syncthreads();

    // ---- FF1: wave w owns n-tiles w*4..w*4+3 ----
    bf16x8s aY[2];
    #pragma unroll
    for (int ks = 0; ks < 2; ++ks) aY[ks] = *(const bf16x8s*)&sYb[lm][ks * 32 + quad * 8];
    #pragma unroll
    for (int u = 0; u < 4; ++u) {
        int j = (w * 4 + u) * 16 + lm;
        f32x4 acc = {0.f, 0.f, 0.f, 0.f};
        const bf16* fr = ffw1T + (size_t)j * 64;
        #pragma unroll
        for (int ks = 0; ks < 2; ++ks) {
            bf16x8s bF = *(const bf16x8s*)&fr[ks * 32 + quad * 8];
            acc = __builtin_amdgcn_mfma_f32_16x16x32_bf16(aY[ks], bF, acc, 0, 0, 0);
        }
        float b1 = ffb1[j];
        #pragma unroll
        for (int r4 = 0; r4 < 4; ++r4)
            sH[quad * 4 + r4][j] = f2b(fmaxf(acc[r4] + b1, 0.f));
    }
    __syncthreads();

    // ---- FF2: wave w owns cols w*16..+15 ----
    f32x4 accF = {0.f, 0.f, 0.f, 0.f};
    const bf16* f2r = ffw2T + (size_t)col * 256;
    #pragma unroll
    for (int ks = 0; ks < 8; ++ks) {
        bf16x8s aH = *(const bf16x8s*)&sH[lm][ks * 32 + quad * 8];
        bf16x8s bF2 = *(const bf16x8s*)&f2r[ks * 32 + quad * 8];
        accF = __builtin_amdgcn_mfma_f32_16x16x32_bf16(aH, bF2, accF, 0, 0, 0);
    }
    float b2 = ffb2[col];
    #pragma unroll
    for (int r4 = 0; r4 < 4; ++r4) {
        int row = quad * 4 + r4;
        sY[row][col] = (accF[r4] + b2) + sY[row][col];   // z = f + y (same-lane in-place)
    }
    __syncthreads();

    // ---- LN2 + store ----
    #pragma unroll
    for (int i = 0; i < 4; ++i) {
        int row = w + 4 * i;
        float z = sY[row][lane];
        float mean = waveSum64(z) * (1.f / 64.f);
        float dv = z - mean;
        float var = waveSum64(dv * dv) * (1.f / 64.f);
        out[((size_t)(b * T) + t0 + row) * KDIM + lane] =
            dv * rsqrtf(var + 1e-5f) * ln2g[lane] + ln2b[lane];
    }
}

extern "C" void kernel_launch(void* const* d_in, const int* in_sizes, int n_in,
                              void* d_out, int out_size, void* d_ws, size_t ws_size,
                              hipStream_t stream) {
    (void)in_sizes; (void)n_in; (void)out_size; (void)ws_size;
    const float* x    = (const float*)d_in[0];
    const float* sqw  = (const float*)d_in[1];
    const float* bng  = (const float*)d_in[2];
    const float* bnb  = (const float*)d_in[3];
    const float* dww  = (const float*)d_in[4];
    const float* exw  = (const float*)d_in[5];
    const float* pos  = (const float*)d_in[6];
    const float* wq   = (const float*)d_in[7];
    const float* bq   = (const float*)d_in[8];
    const float* wk   = (const float*)d_in[9];
    const float* bk   = (const float*)d_in[10];
    const float* wv   = (const float*)d_in[11];
    const float* wl   = (const float*)d_in[12];
    const float* uniw = (const float*)d_in[13];
    const float* unib = (const float*)d_in[14];
    const float* ln1g = (const float*)d_in[15];
    const float* ln1b = (const float*)d_in[16];
    const float* ln2g = (const float*)d_in[17];
    const float* ln2b = (const float*)d_in[18];
    const float* ffw1 = (const float*)d_in[19];
    const float* ffb1 = (const float*)d_in[20];
    const float* ffw2 = (const float*)d_in[21];
    const float* ffb2 = (const float*)d_in[22];

    // ws layout — ~22.5 MiB.
    char* ws = (char*)d_ws;
    float* xin   = (float*)(ws);                  // fp32 1.0 MiB
    bf16*  qog   = (bf16*)(ws + 0x100000);        // 4 MiB  q, then og in-place
    bf16*  kw_   = (bf16*)(ws + 0x500000);        // 4 MiB
    bf16*  vw_   = (bf16*)(ws + 0x900000);        // 4 MiB
    bf16*  lw_   = (bf16*)(ws + 0xD00000);        // 4 MiB
    bf16*  olw   = (bf16*)(ws + 0x1100000);       // 4 MiB
    float* x3    = (float*)(ws + 0x1500000);      // fp32 0.5 MiB
    bf16*  BqT   = (bf16*)(ws + 0x1580000);       // 320 KiB
    bf16*  BkT   = (bf16*)(ws + 0x15D0000);       // 320 KiB
    bf16*  BvT   = (bf16*)(ws + 0x1620000);       // 64 KiB
    bf16*  BlT   = (bf16*)(ws + 0x1630000);       // 64 KiB
    bf16*  uniwT = (bf16*)(ws + 0x1640000);       // 128 KiB
    bf16*  ffw1T = (bf16*)(ws + 0x1660000);       // 32 KiB
    bf16*  ffw2T = (bf16*)(ws + 0x1668000);       // 32 KiB (end 0x1670000)

    k1a_x3 <<<512, 256, 0, stream>>>(x, sqw, bng, bnb, wq, wk, wv, wl, uniw, ffw1, ffw2,
                                     x3, BqT, BkT, BvT, BlT, uniwT, ffw1T, ffw2T);
    k1b_xin<<<512, 256, 0, stream>>>(x3, dww, exw, x, pos, xin);
    k2_mfma<<<512, 256, 0, stream>>>(xin, BqT, BkT, BvT, BlT, bq, bk, qog, kw_, vw_, lw_);
    k3_local<<<8192, 256, 0, stream>>>(lw_, olw);
    k4_mfma<<<512, 256, 0, stream>>>(qog, kw_, vw_, qog);   // og overwrites q in-place
    k5_mfma<<<256, 256, 0, stream>>>(qog, olw, uniwT, unib, xin,
                                     ln1g, ln1b, ffw1T, ffb1, ffw2T, ffb2, ln2g, ln2b,
                                     (float*)d_out);
}